// Round 7
// baseline (1374.051 us; speedup 1.0000x reference)
//
#include <hip/hip_runtime.h>
#include <math.h>

#define B_   2
#define T_   1024
#define D_   1024
#define H_   16
#define DH_  64
#define DFF_ 4096
#define V_   32000
#define NTOK 2046      // B*(T-1)
#define NCH  250       // V_/128 vocab chunks for loss partials

typedef __attribute__((ext_vector_type(8))) short short8;
typedef __attribute__((ext_vector_type(4))) float floatx4;

__device__ __forceinline__ unsigned short f2bf(float x) {
    unsigned int u = __float_as_uint(x);
    unsigned int r = (u + 0x7fffu + ((u >> 16) & 1u)) >> 16;
    return (unsigned short)r;
}

__device__ __forceinline__ float bf2f(unsigned short u) {
    return __uint_as_float((unsigned int)u << 16);
}

__device__ __forceinline__ void gld_lds16(void* lds, const void* g) {
    __builtin_amdgcn_global_load_lds(
        (const __attribute__((address_space(1))) void*)g,
        (__attribute__((address_space(3))) void*)lds, 16, 0, 0);
}

__device__ __forceinline__ float gelu_tanh(float x) {
    float x3 = x * x * x;
    return 0.5f * x * (1.0f + tanhf(0.7978845608028654f * (x + 0.044715f * x3)));
}

// ---------------- weight prep: out[n*K+k] = bf16(W[k*N+n] + 2*(A@Bm)[k,n]) ----------------
__global__ __launch_bounds__(256) void k_prep_w(const float* __restrict__ W,
        const float* __restrict__ A, const float* __restrict__ Bm,
        unsigned short* __restrict__ out, int K, int N, int lora) {
    __shared__ float t[64][65];
    int n0 = blockIdx.x * 64, k0 = blockIdx.y * 64;
    int tid = threadIdx.x;
    int nn = tid & 63, kb = tid >> 6;
    for (int i = 0; i < 16; i++) {
        int kk = kb * 16 + i;
        float v = W[(size_t)(k0 + kk) * N + n0 + nn];
        if (lora) {
            float s = 0.f;
#pragma unroll
            for (int r = 0; r < 8; r++) s += A[(k0 + kk) * 8 + r] * Bm[r * N + n0 + nn];
            v += 2.0f * s;
        }
        t[kk][nn] = v;
    }
    __syncthreads();
    int kk2 = tid & 63, nb = tid >> 6;
    for (int j = 0; j < 16; j++) {
        int nn2 = nb * 16 + j;
        out[(size_t)(n0 + nn2) * K + k0 + kk2] = f2bf(t[kk2][nn2]);
    }
}

// ---------------- fp32 -> bf16 bulk convert ----------------
__global__ void k_f2bf(const float* __restrict__ in, unsigned short* __restrict__ out, int n4) {
    int i = blockIdx.x * 256 + threadIdx.x;
    if (i >= n4) return;
    float4 v = ((const float4*)in)[i];
    ushort4 o;
    o.x = f2bf(v.x); o.y = f2bf(v.y); o.z = f2bf(v.z); o.w = f2bf(v.w);
    ((ushort4*)out)[i] = o;
}

// ---------------- embedding gather ----------------
__global__ void k_embed_gather(const int* __restrict__ ids, const float* __restrict__ embed,
                               float* __restrict__ embeds) {
    int bt = blockIdx.x;
    int d4 = threadIdx.x;
    int id = ids[bt];
    ((float4*)embeds)[(size_t)bt * 256 + d4] = ((const float4*)embed)[(size_t)id * 256 + d4];
}

// ---------------- LayerNorm. If embeds!=null: x = embeds+Wpos (writes hout); else x = in. ----------------
__global__ __launch_bounds__(256) void k_ln(const float* __restrict__ in,
                                            const float* __restrict__ embeds, const float* __restrict__ Wpos,
                                            const float* __restrict__ sc, const float* __restrict__ bi,
                                            float* __restrict__ hout, float* __restrict__ outf,
                                            unsigned short* __restrict__ outbf,
                                            int c0, int range, int strided_bf) {
    int r = blockIdx.x;
    int b = r / range, pos = c0 + r % range;
    size_t rowoff = (size_t)(b * T_ + pos) * D_;
    int tid = threadIdx.x;
    float xv[4];
    if (embeds) {
#pragma unroll
        for (int j = 0; j < 4; j++) {
            int i = tid + j * 256;
            xv[j] = embeds[rowoff + i] + Wpos[(size_t)pos * D_ + i];
            hout[rowoff + i] = xv[j];
        }
    } else {
#pragma unroll
        for (int j = 0; j < 4; j++) xv[j] = in[rowoff + tid + j * 256];
    }
    float s1 = 0.f, s2 = 0.f;
#pragma unroll
    for (int j = 0; j < 4; j++) { s1 += xv[j]; s2 += xv[j] * xv[j]; }
    __shared__ float r1[256], r2[256];
    r1[tid] = s1; r2[tid] = s2; __syncthreads();
    for (int o = 128; o > 0; o >>= 1) {
        if (tid < o) { r1[tid] += r1[tid + o]; r2[tid] += r2[tid + o]; }
        __syncthreads();
    }
    float mean = r1[0] * (1.0f / D_);
    float var = r2[0] * (1.0f / D_) - mean * mean;
    float inv = rsqrtf(var + 1e-5f);
    size_t bfrow = strided_bf ? (size_t)(b * T_ + pos) : (size_t)r;
#pragma unroll
    for (int j = 0; j < 4; j++) {
        int i = tid + j * 256;
        float y = (xv[j] - mean) * inv * sc[i] + bi[i];
        if (outf) outf[rowoff + i] = y;
        outbf[bfrow * D_ + i] = f2bf(y);
    }
}

// ---------------- MFMA GEMM: C[M,N] = A[M,K](bf16) @ Bt[N,K]^T(bf16) ----------------
// 64x128 block tile (r6-proven): 2x2 waves of 32x64, acc[2][4] (32 AGPR),
// ~1.5-2 blocks/CU on pass grids. Latency-bound regime: blocks/CU is the lever.
// MODE 1: qkv scatter -> bf16 q / k cache / v cache (u2=vcbf)
// MODE 2: split-K atomic residual add fp32 (grid.z = K segments)
// MODE 3: gelu -> bf16
template <int MODE>
__global__ __launch_bounds__(256) void k_mgemm(const unsigned short* __restrict__ Abf,
        const unsigned short* __restrict__ Bt, const float* __restrict__ bias,
        float* __restrict__ o0, unsigned short* __restrict__ u0,
        unsigned short* __restrict__ u1, unsigned short* __restrict__ u2,
        int M, int N, int K, int c0, int range, int ksegs) {
    __shared__ short8 As_v[256];   // [kg 0..3][row 0..63]
    __shared__ short8 Bs_v[512];   // [kg 0..3][col 0..127]
    int tid = threadIdx.x;
    int lane = tid & 63, w = tid >> 6;
    int quad = lane >> 4, l15 = lane & 15;
    int row0 = blockIdx.y * 64, col0 = blockIdx.x * 128;
    int kseg = blockIdx.z;
    int Klen = K / ksegs;
    int ksoff = kseg * Klen;
    int wr = w >> 1, wc = w & 1;   // wave sub-tile: rows wr*32.., cols wc*64..

    int arow = row0 + lane; if (arow >= M) arow = M - 1;
    const unsigned short* ga  = Abf + (size_t)arow * K + ksoff + w * 8;
    int bcol = col0 + (w & 1) * 64 + lane;
    const unsigned short* gb1 = Bt + (size_t)bcol * K + ksoff + (w >> 1) * 8;
    const unsigned short* gb2 = Bt + (size_t)bcol * K + ksoff + (2 + (w >> 1)) * 8;

    floatx4 acc[2][4];
#pragma unroll
    for (int i = 0; i < 2; i++)
#pragma unroll
        for (int j = 0; j < 4; j++)
#pragma unroll
            for (int k = 0; k < 4; k++) acc[i][j][k] = 0.f;

    int iters = Klen >> 5;
    for (int it = 0; it < iters; ++it) {
        __syncthreads();
        gld_lds16(&As_v[w * 64],        ga);
        gld_lds16(&Bs_v[w * 64],        gb1);
        gld_lds16(&Bs_v[256 + w * 64],  gb2);
        ga += 32; gb1 += 32; gb2 += 32;
        __syncthreads();
        short8 af[2], bfv[4];
#pragma unroll
        for (int mi = 0; mi < 2; mi++) af[mi] = As_v[quad * 64 + wr * 32 + mi * 16 + l15];
#pragma unroll
        for (int nj = 0; nj < 4; nj++) bfv[nj] = Bs_v[quad * 128 + wc * 64 + nj * 16 + l15];
#pragma unroll
        for (int mi = 0; mi < 2; mi++)
#pragma unroll
            for (int nj = 0; nj < 4; nj++)
                acc[mi][nj] = __builtin_amdgcn_mfma_f32_16x16x32_bf16(af[mi], bfv[nj], acc[mi][nj], 0, 0, 0);
    }

#pragma unroll
    for (int mi = 0; mi < 2; mi++)
#pragma unroll
        for (int reg = 0; reg < 4; reg++) {
            int r = row0 + wr * 32 + mi * 16 + quad * 4 + reg;
            if (r >= M) continue;
            int b = r / range, pos = c0 + r % range;
#pragma unroll
            for (int nj = 0; nj < 4; nj++) {
                int n = col0 + wc * 64 + nj * 16 + l15;
                if constexpr (MODE == 1) {
                    float v = acc[mi][nj][reg] + bias[n];
                    if (n < 1024) u0[(size_t)r * 1024 + n] = f2bf(v);
                    else if (n < 2048) u1[(size_t)(b * T_ + pos) * 1024 + (n - 1024)] = f2bf(v);
                    else u2[(size_t)(b * T_ + pos) * 1024 + (n - 2048)] = f2bf(v);
                } else if constexpr (MODE == 2) {
                    float v = acc[mi][nj][reg] + (kseg == 0 ? bias[n] : 0.f);
                    atomicAdd(&o0[(size_t)(b * T_ + pos) * D_ + n], v);
                } else if constexpr (MODE == 3) {
                    float v = acc[mi][nj][reg] + bias[n];
                    u0[(size_t)r * N + n] = f2bf(gelu_tanh(v));
                }
            }
        }
}

// ---------------- small-M (Mr=2) VALU dot GEMM for the range==1 passes ----------------
// MODE 4: qkv scatter (q->u0, k->u1, v DIRECT into transposed vtc u2)
// MODE 2: residual add fp32 into o0
// MODE 3: gelu -> bf16 u0 (rowstride N)
template <int MODE>
__global__ __launch_bounds__(256) void k_sgemm(const unsigned short* __restrict__ Abf,
        const unsigned short* __restrict__ Bt, const float* __restrict__ bias,
        float* __restrict__ o0, unsigned short* __restrict__ u0,
        unsigned short* __restrict__ u1, unsigned short* __restrict__ u2,
        int N, int K, int c0) {
    __shared__ unsigned short lds_a[2 * 4096];   // 2 rows x K (K<=4096), contiguous
    __shared__ float lds_p[4][64][2];
    int tid = threadIdx.x, lane = tid & 63, w = tid >> 6;
    int n = blockIdx.x * 64 + lane;
    // stage A: rows are contiguous (rowstride == K for every caller)
    int nv = (2 * K) >> 3;
    for (int v = tid; v < nv; v += 256)
        *(short8*)&lds_a[v * 8] = *(const short8*)&Abf[v * 8];
    __syncthreads();
    int kq = K >> 2;           // this wave's K-range
    int k0 = w * kq;
    float a0 = 0.f, a1 = 0.f;
    const unsigned short* bp = Bt + (size_t)n * K + k0;
    for (int i = 0; i < kq; i += 8) {
        short8 bv  = *(const short8*)(bp + i);
        short8 av0 = *(const short8*)&lds_a[k0 + i];
        short8 av1 = *(const short8*)&lds_a[K + k0 + i];
#pragma unroll
        for (int j = 0; j < 8; j++) {
            float bf_ = bf2f((unsigned short)bv[j]);
            a0 += bf2f((unsigned short)av0[j]) * bf_;
            a1 += bf2f((unsigned short)av1[j]) * bf_;
        }
    }
    lds_p[w][lane][0] = a0;
    lds_p[w][lane][1] = a1;
    __syncthreads();
    if (tid < 128) {
        int l = tid & 63, m = tid >> 6;          // m = row = batch (range==1)
        int nn = blockIdx.x * 64 + l;
        float acc = lds_p[0][l][m] + lds_p[1][l][m] + lds_p[2][l][m] + lds_p[3][l][m];
        int b = m, pos = c0;
        if constexpr (MODE == 4) {
            float v = acc + bias[nn];
            if (nn < 1024) u0[(size_t)m * 1024 + nn] = f2bf(v);
            else if (nn < 2048) u1[(size_t)(b * T_ + pos) * 1024 + (nn - 1024)] = f2bf(v);
            else {
                int idx = nn - 2048, h = idx >> 6, d = idx & 63;
                u2[(size_t)((b * 16 + h) * 64 + d) * T_ + pos] = f2bf(v);
            }
        } else if constexpr (MODE == 2) {
            o0[(size_t)(b * T_ + pos) * D_ + nn] += acc + bias[nn];
        } else if constexpr (MODE == 3) {
            u0[(size_t)m * N + nn] = f2bf(gelu_tanh(acc + bias[nn]));
        }
    }
}

// ---------------- V transpose into global vtc[(b*16+h)*64+d][T] (big passes) ----------------
__global__ __launch_bounds__(256) void k_vtrans(const unsigned short* __restrict__ vcbf,
        unsigned short* __restrict__ vtc, int c0, int range) {
    __shared__ unsigned short ts[64][72];
    int pt = blockIdx.x, h = blockIdx.y, b = blockIdx.z;
    int t = threadIdx.x;
#pragma unroll
    for (int i = 0; i < 2; i++) {
        int idx = t + i * 256;
        int p = idx >> 3, c8 = idx & 7;
        int pos = c0 + pt * 64 + p;
        if (pos < c0 + range) {
            short8 v = *(const short8*)&vcbf[(size_t)(b * T_ + pos) * D_ + h * 64 + c8 * 8];
            *(short8*)&ts[p][c8 * 8] = v;
        }
    }
    __syncthreads();
#pragma unroll
    for (int i = 0; i < 2; i++) {
        int idx = t + i * 256;
        int d = idx >> 3, p8 = idx & 7;
        unsigned short tmp[8];
#pragma unroll
        for (int j = 0; j < 8; j++) tmp[j] = ts[p8 * 8 + j][d];
        int pos0 = c0 + pt * 64 + p8 * 8;
        size_t rb = (size_t)((b * 16 + h) * 64 + d) * T_;
        if (pos0 + 7 < c0 + range) {
            *(short8*)&vtc[rb + pos0] = *(short8*)tmp;
        } else {
            for (int j = 0; j < 8; j++)
                if (pos0 + j < c0 + range) vtc[rb + pos0 + j] = tmp[j];
        }
    }
}

// ---------------- barrier-free MFMA flash attention ----------------
__global__ __launch_bounds__(256) void k_fattn(const unsigned short* __restrict__ qbf,
        const unsigned short* __restrict__ kcbf, const unsigned short* __restrict__ vtc,
        unsigned short* __restrict__ ctxbf, int c0, int range) {
    __shared__ unsigned short pw[4][16][72];
    int tid = threadIdx.x;
    int w = tid >> 6, lane = tid & 63, quad = lane >> 4, l15 = lane & 15;
    int qt = blockIdx.x, h = blockIdx.y, b = blockIdx.z;
    int q0 = qt * 64 + w * 16;
    if (q0 >= range) return;                 // no barriers in this kernel -> safe
    int qtop = q0 + 15; if (qtop >= range) qtop = range - 1;
    int nkt = (c0 + qtop) / 64 + 1;

    int qrow = q0 + l15; if (qrow >= range) qrow = range - 1;
    const unsigned short* qp = qbf + (size_t)(b * range + qrow) * D_ + h * 64 + quad * 8;
    short8 aq0 = *(const short8*)qp;
    short8 aq1 = *(const short8*)(qp + 32);

    floatx4 oacc[4];
#pragma unroll
    for (int dg = 0; dg < 4; dg++)
#pragma unroll
        for (int r = 0; r < 4; r++) oacc[dg][r] = 0.f;
    float m_r[4] = {-1e30f, -1e30f, -1e30f, -1e30f};
    float l_r[4] = {0.f, 0.f, 0.f, 0.f};

    const unsigned short* kb_p = kcbf + (size_t)b * T_ * D_ + h * 64 + quad * 8;
    const unsigned short* vb_p = vtc + (size_t)((b * 16 + h) * 64 + l15) * T_ + quad * 8;

    for (int kt = 0; kt < nkt; kt++) {
        int kb = kt * 64;
        floatx4 s[4];
#pragma unroll
        for (int g = 0; g < 4; g++) {
            const unsigned short* kp = kb_p + (size_t)(kb + g * 16 + l15) * D_;
            short8 bk0 = *(const short8*)kp;
            short8 bk1 = *(const short8*)(kp + 32);
            floatx4 z; z[0] = 0.f; z[1] = 0.f; z[2] = 0.f; z[3] = 0.f;
            z = __builtin_amdgcn_mfma_f32_16x16x32_bf16(aq0, bk0, z, 0, 0, 0);
            s[g] = __builtin_amdgcn_mfma_f32_16x16x32_bf16(aq1, bk1, z, 0, 0, 0);
        }
#pragma unroll
        for (int r = 0; r < 4; r++) {
            int qpos = c0 + q0 + quad * 4 + r;
            float mx = -1e30f;
#pragma unroll
            for (int g = 0; g < 4; g++) {
                int kpos = kb + g * 16 + l15;
                float sv = (kpos <= qpos) ? s[g][r] * 0.125f : -1e30f;
                s[g][r] = sv; mx = fmaxf(mx, sv);
            }
            mx = fmaxf(mx, __shfl_xor(mx, 1));
            mx = fmaxf(mx, __shfl_xor(mx, 2));
            mx = fmaxf(mx, __shfl_xor(mx, 4));
            mx = fmaxf(mx, __shfl_xor(mx, 8));
            float mn = fmaxf(m_r[r], mx);
            float alpha = __expf(m_r[r] - mn);
            m_r[r] = mn;
            float ls = 0.f;
#pragma unroll
            for (int g = 0; g < 4; g++) {
                float p = __expf(s[g][r] - mn);
                s[g][r] = p; ls += p;
            }
            ls += __shfl_xor(ls, 1);
            ls += __shfl_xor(ls, 2);
            ls += __shfl_xor(ls, 4);
            ls += __shfl_xor(ls, 8);
            l_r[r] = l_r[r] * alpha + ls;
#pragma unroll
            for (int dg = 0; dg < 4; dg++) oacc[dg][r] *= alpha;
        }
#pragma unroll
        for (int g = 0; g < 4; g++)
#pragma unroll
            for (int r = 0; r < 4; r++)
                pw[w][quad * 4 + r][g * 16 + l15] = f2bf(s[g][r]);
        short8 ap0 = *(const short8*)&pw[w][l15][quad * 8];
        short8 ap1 = *(const short8*)&pw[w][l15][32 + quad * 8];
#pragma unroll
        for (int dg = 0; dg < 4; dg++) {
            const unsigned short* vp = vb_p + (size_t)(dg * 16) * T_ + kb;
            short8 bv0 = *(const short8*)vp;
            short8 bv1 = *(const short8*)(vp + 32);
            oacc[dg] = __builtin_amdgcn_mfma_f32_16x16x32_bf16(ap0, bv0, oacc[dg], 0, 0, 0);
            oacc[dg] = __builtin_amdgcn_mfma_f32_16x16x32_bf16(ap1, bv1, oacc[dg], 0, 0, 0);
        }
    }
#pragma unroll
    for (int dg = 0; dg < 4; dg++)
#pragma unroll
        for (int r = 0; r < 4; r++) {
            int qloc = q0 + quad * 4 + r;
            if (qloc < range)
                ctxbf[(size_t)(b * range + qloc) * D_ + h * 64 + dg * 16 + l15] =
                    f2bf(oacc[dg][r] / l_r[r]);
        }
}

// ---------------- latent vec fills ----------------
__global__ void k_latent0(const float* __restrict__ hid, const float* __restrict__ lw,
                          float* __restrict__ embeds) {
    int idx = blockIdx.x * 256 + threadIdx.x;
    if (idx >= B_ * D_) return;
    int b = idx / D_, d = idx % D_;
    float w0 = lw[0], w1 = lw[1], w2 = lw[2];
    float mx = fmaxf(w0, fmaxf(w1, w2));
    float e0 = __expf(w0 - mx), e1 = __expf(w1 - mx), e2 = __expf(w2 - mx);
    float inv = 1.0f / (e0 + e1 + e2);
    float v = (e0 * hid[(size_t)(b * T_ + 509) * D_ + d] +
               e1 * hid[(size_t)(b * T_ + 510) * D_ + d] +
               e2 * hid[(size_t)(b * T_ + 511) * D_ + d]) * inv;
    embeds[(size_t)(b * T_ + 512) * D_ + d] = v;
}

__global__ void k_latent1(const float* __restrict__ hid, float* __restrict__ embeds, int tok) {
    int idx = blockIdx.x * 256 + threadIdx.x;
    if (idx >= B_ * D_) return;
    int b = idx / D_, d = idx % D_;
    embeds[(size_t)(b * T_ + tok) * D_ + d] = hid[(size_t)(b * T_ + tok - 1) * D_ + d];
}

// ---------------- loss MFMA GEMM: 64x128 tile (r6 k_mgemm structure) ----------------
// r0 128x128 loop = 293us at 2.6 blocks/CU (latency-bound at barrier, 68% idle).
// Same retile that won on the passes: acc[2][4] (32 AGPR) -> 4 waves/SIMD,
// grid 8000 blocks -> ~4-5 blocks/CU of independent barrier groups.
// Staging/fragment map identical to harness-verified k_mgemm; epilogue
// remapped to 64 rows with per-wave col-half partials.
__global__ __launch_bounds__(256) void k_loss1m(const unsigned short* __restrict__ hidbf,
        const unsigned short* __restrict__ embedbf, const int* __restrict__ labels,
        float* __restrict__ partm, float* __restrict__ parts, float* __restrict__ llogit) {
    __shared__ short8 As_v[256];   // [kg 0..3][row 0..63]
    __shared__ short8 Bs_v[512];   // [kg 0..3][col 0..127]
    __shared__ int lds_lab[64];
    __shared__ float lds_pm[64][2];
    __shared__ float lds_ps[64][2];
    int tid = threadIdx.x;
    int lane = tid & 63, w = tid >> 6;
    int quad = lane >> 4, l15 = lane & 15;
    int chunk = blockIdx.y;                     // y = vocab chunk (128 cols)
    int row0 = blockIdx.x * 64, v0 = chunk * 128;
    int wr = w >> 1, wc = w & 1;                // wave sub-tile: rows wr*32.., cols wc*64..

    if (tid < 64) {
        int tok = row0 + tid;
        lds_lab[tid] = (tok < NTOK) ? labels[tok + 1 + (tok >= 1023)] : -1;
    }

    int tokA = row0 + lane; if (tokA >= NTOK) tokA = NTOK - 1;
    const unsigned short* ga  = hidbf + (size_t)(tokA + (tokA >= 1023)) * D_ + w * 8;
    int bcol = v0 + (w & 1) * 64 + lane;
    const unsigned short* gb1 = embedbf + (size_t)bcol * D_ + (w >> 1) * 8;
    const unsigned short* gb2 = embedbf + (size_t)bcol * D_ + (2 + (w >> 1)) * 8;

    floatx4 acc[2][4];
#pragma unroll
    for (int i = 0; i < 2; i++)
#pragma unroll
        for (int j = 0; j < 4; j++)
#pragma unroll
            for (int k = 0; k < 4; k++) acc[i][j][k] = 0.f;

    for (int it = 0; it < D_ / 32; ++it) {
        __syncthreads();
        gld_lds16(&As_v[w * 64],        ga);
        gld_lds16(&Bs_v[w * 64],        gb1);
        gld_lds16(&Bs_v[256 + w * 64],  gb2);
        ga += 32; gb1 += 32; gb2 += 32;
        __syncthreads();
        short8 af[2], bfv[4];
#pragma unroll
        for (int mi = 0; mi < 2; mi++) af[mi] = As_v[quad * 64 + wr * 32 + mi * 16 + l15];
#pragma unroll
        for (int nj = 0; nj < 4; nj++) bfv[nj] = Bs_v[quad * 128 + wc * 64 + nj * 16 + l15];
#pragma unroll
        for (int mi = 0; mi < 2; mi++)
#pragma unroll
            for (int nj = 0; nj < 4; nj++)
                acc[mi][nj] = __builtin_amdgcn_mfma_f32_16x16x32_bf16(af[mi], bfv[nj], acc[mi][nj], 0, 0, 0);
    }

    // per-row partials over this wave's 64 cols; two waves (wc=0/1) cover the
    // chunk's 128 cols for each 32-row band -> lds_pm[rloc][wc].
#pragma unroll
    for (int mi = 0; mi < 2; mi++)
#pragma unroll
        for (int reg = 0; reg < 4; reg++) {
            int rloc = wr * 32 + mi * 16 + quad * 4 + reg;
            int lab = lds_lab[rloc];
            float vm = -1e30f;
#pragma unroll
            for (int nj = 0; nj < 4; nj++) {
                float v = acc[mi][nj][reg];
                int vcol = v0 + wc * 64 + nj * 16 + l15;
                if (vcol == lab) llogit[row0 + rloc] = v;
                vm = fmaxf(vm, v);
            }
            for (int off = 1; off < 16; off <<= 1) vm = fmaxf(vm, __shfl_xor(vm, off));
            float ss = 0.f;
#pragma unroll
            for (int nj = 0; nj < 4; nj++) ss += __expf(acc[mi][nj][reg] - vm);
            for (int off = 1; off < 16; off <<= 1) ss += __shfl_xor(ss, off);
            if (l15 == 0) { lds_pm[rloc][wc] = vm; lds_ps[rloc][wc] = ss; }
        }
    __syncthreads();
    if (tid < 64) {
        int tok = row0 + tid;
        if (tok < NTOK) {
            float m0 = lds_pm[tid][0], m1 = lds_pm[tid][1];
            float M = fmaxf(m0, m1);
            float S = lds_ps[tid][0] * __expf(m0 - M) + lds_ps[tid][1] * __expf(m1 - M);
            partm[(size_t)chunk * NTOK + tok] = M;
            parts[(size_t)chunk * NTOK + tok] = S;
        }
    }
}

// ---------------- loss combine ----------------
__global__ void k_loss2a(const float* __restrict__ partm, const float* __restrict__ parts,
                         const float* __restrict__ ll, float* __restrict__ nll) {
    int tok = blockIdx.x * 256 + threadIdx.x;
    if (tok >= NTOK) return;
    float M = -1e30f;
    for (int c = 0; c < NCH; c++) M = fmaxf(M, partm[(size_t)c * NTOK + tok]);
    float S = 0.f;
    for (int c = 0; c < NCH; c++)
        S += parts[(size_t)c * NTOK + tok] * __expf(partm[(size_t)c * NTOK + tok] - M);
    nll[tok] = logf(S) + M - ll[tok];
}

__global__ __launch_bounds__(256) void k_loss2b(const float* __restrict__ nll, float* __restrict__ out) {
    __shared__ float red[256];
    int tid = threadIdx.x;
    float s = 0.f;
    for (int i = tid; i < NTOK; i += 256) s += nll[i];
    red[tid] = s; __syncthreads();
    for (int o = 128; o > 0; o >>= 1) {
        if (tid < o) red[tid] += red[tid + o];
        __syncthreads();
    }
    if (tid == 0) out[0] = red[0] / (float)NTOK;
}

// ---------------- host ----------------
extern "C" void kernel_launch(void* const* d_in, const int* in_sizes, int n_in,
                              void* d_out, int out_size, void* d_ws, size_t ws_size,
                              hipStream_t stream) {
    const int*   input_ids = (const int*)d_in[0];
    const int*   labels    = (const int*)d_in[2];
    const float* embed     = (const float*)d_in[4];
    const float* Wpos      = (const float*)d_in[5];
    const float* Wqkv      = (const float*)d_in[6];
    const float* bqkv      = (const float*)d_in[7];
    const float* Aq        = (const float*)d_in[8];
    const float* Bq        = (const float*)d_in[9];
    const float* Wo        = (const float*)d_in[10];
    const float* bo        = (const float*)d_in[11];
    const float* Ao        = (const float*)d_in[12];
    const float* Bo        = (const float*)d_in[13];
    const float* W1        = (const float*)d_in[14];
    const float* b1        = (const float*)d_in[15];
    const float* W2        = (const float*)d_in[16];
    const float* b2        = (const float*)d_in[17];
    const float* ln1_s     = (const float*)d_in[18];
    const float* ln1_b     = (const float*)d_in[19];
    const float* ln2_s     = (const float*)d_in[20];
    const float* ln2_b     = (const float*)d_in[21];
    const float* lnf_s     = (const float*)d_in[22];
    const float* lnf_b     = (const float*)d_in[23];
    const float* latent_w  = (const float*)d_in[24];

    char* base = (char*)d_ws;
    size_t off = 0;
    auto alloc = [&](size_t bytes) { void* p = base + off; off += (bytes + 255) & ~255ULL; return p; };

    float* embeds  = (float*)alloc((size_t)B_ * T_ * D_ * 4);
    float* hbuf    = (float*)alloc((size_t)B_ * T_ * D_ * 4);
    float* hidbuf  = (float*)alloc((size_t)B_ * T_ * D_ * 4);
    float* partm   = (float*)alloc((size_t)NCH * NTOK * 4);
    float* parts_  = (float*)alloc((size_t)NCH * NTOK * 4);
    float* llogit  = (float*)alloc((size_t)NTOK * 4);
    float* nllbuf  = (float*)alloc((size_t)NTOK * 4);
    unsigned short* wqkvT  = (unsigned short*)alloc((size_t)3072 * 1024 * 2);
    unsigned short* woT    = (unsigned short*)alloc((size_t)1024 * 1024 * 2);
    unsigned short* W1T    = (unsigned short*)alloc((size_t)4096 * 1024 * 2);
    unsigned short* W2T    = (unsigned short*)alloc((size_t)1024 * 4096 * 2);
    unsigned short* embedbf = (unsigned short*)alloc((size_t)V_ * D_ * 2);
    unsigned short* hidbf  = (unsigned short*)alloc((size_t)B_ * T_ * D_ * 2);
    unsigned short* abf    = (unsigned short*)alloc((size_t)1024 * D_ * 2);
    unsigned short* ctxbf  = (unsigned short*)alloc((size_t)1024 * D_ * 2);
    unsigned short* ffbw   = (unsigned short*)alloc((size_t)1024 * DFF_ * 2);
    unsigned short* qbf    = (unsigned short*)alloc((size_t)1024 * D_ * 2);
    unsigned short* kcbf   = (unsigned short*)alloc((size_t)B_ * T_ * D_ * 2);
    unsigned short* vcbf   = (unsigned short*)alloc((size_t)B_ * T_ * D_ * 2);
    unsigned short* vtc    = (unsigned short*)alloc((size_t)B_ * H_ * DH_ * T_ * 2);

    // weight prep (transpose + LoRA merge + bf16)
    k_prep_w<<<dim3(3072 / 64, 1024 / 64), 256, 0, stream>>>(Wqkv, Aq, Bq, wqkvT, 1024, 3072, 1);
    k_prep_w<<<dim3(1024 / 64, 1024 / 64), 256, 0, stream>>>(Wo, Ao, Bo, woT, 1024, 1024, 1);
    k_prep_w<<<dim3(4096 / 64, 1024 / 64), 256, 0, stream>>>(W1, nullptr, nullptr, W1T, 1024, 4096, 0);
    k_prep_w<<<dim3(1024 / 64, 4096 / 64), 256, 0, stream>>>(W2, nullptr, nullptr, W2T, 4096, 1024, 0);
    k_f2bf<<<(V_ * D_ / 4 + 255) / 256, 256, 0, stream>>>(embed, embedbf, V_ * D_ / 4);
    k_embed_gather<<<B_ * T_, 256, 0, stream>>>(input_ids, embed, embeds);

    auto run_pass = [&](int c0, int c1) {
        int range = c1 - c0;
        int Mr = B_ * range;
        int gy = (Mr + 63) / 64;
        int qt = (range + 63) / 64;
        // ln1 (fused h = embeds + Wpos -> hbuf)
        k_ln<<<Mr, 256, 0, stream>>>(nullptr, embeds, Wpos, ln1_s, ln1_b, hbuf, nullptr, abf, c0, range, 0);
        if (range == 1) {
            // small-M path: VALU dot kernels, v scattered directly into vtc
            k_sgemm<4><<<3072 / 64, 256, 0, stream>>>(abf, wqkvT, bqkv, nullptr, qbf, kcbf, vtc,
                                                      3072, 1024, c0);
            k_fattn<<<dim3(1, H_, B_), 256, 0, stream>>>(qbf, kcbf, vtc, ctxbf, c0, 1);
            k_sgemm<2><<<1024 / 64, 256, 0, stream>>>(ctxbf, woT, bo, hbuf, nullptr, nullptr, nullptr,
                                                      1024, 1024, c0);
            k_ln<<<Mr, 256, 0, stream>>>(hbuf, nullptr, nullptr, ln2_s, ln2_b, nullptr, nullptr, abf, c0, range, 0);
            k_sgemm<3><<<4096 / 64, 256, 0, stream>>>(abf, W1T, b1, nullptr, ffbw, nullptr, nullptr,
                                                      4096, 1024, c0);
            k_sgemm<2><<<1024 / 64, 256, 0, stream>>>(ffbw, W2T, b2, hbuf, nullptr, nullptr, nullptr,
                                                      1024, 4096, c0);
        } else {
            k_mgemm<1><<<dim3(3072 / 128, gy), 256, 0, stream>>>(abf, wqkvT, bqkv, nullptr, qbf, kcbf, vcbf,
                                                                 Mr, 3072, 1024, c0, range, 1);
            k_vtrans<<<dim3(qt, H_, B_), 256, 0, stream>>>(vcbf, vtc, c0, range);
            k_fattn<<<dim3(qt, H_, B_), 256, 0, stream>>>(qbf, kcbf, vtc, ctxbf, c0, range);
            k_mgemm<2><<<dim3(1024 / 128, gy, 4), 256, 0, stream>>>(ctxbf, woT, bo, hbuf, nullptr, nullptr, nullptr,
                                                                    Mr, 1024, 1024, c0, range, 4);
            k_ln<<<Mr, 256, 0, stream>>>(hbuf, nullptr, nullptr, ln2_s, ln2_b, nullptr, nullptr, abf, c0, range, 0);
            k_mgemm<3><<<dim3(4096 / 128, gy), 256, 0, stream>>>(abf, W1T, b1, nullptr, ffbw, nullptr, nullptr,
                                                                 Mr, 4096, 1024, c0, range, 1);
            k_mgemm<2><<<dim3(1024 / 128, gy, 4), 256, 0, stream>>>(ffbw, W2T, b2, hbuf, nullptr, nullptr, nullptr,
                                                                    Mr, 1024, 4096, c0, range, 4);
        }
        k_ln<<<Mr, 256, 0, stream>>>(hbuf, nullptr, nullptr, lnf_s, lnf_b, nullptr, hidbuf, hidbf, c0, range, 1);
    };

    run_pass(0, 512);
    k_latent0<<<(B_ * D_ + 255) / 256, 256, 0, stream>>>(hidbuf, latent_w, embeds);
    run_pass(512, 513);
    k_latent1<<<(B_ * D_ + 255) / 256, 256, 0, stream>>>(hidbuf, embeds, 513);
    run_pass(513, 514);
    k_latent1<<<(B_ * D_ + 255) / 256, 256, 0, stream>>>(hidbuf, embeds, 514);
    run_pass(514, 515);
    k_latent1<<<(B_ * D_ + 255) / 256, 256, 0, stream>>>(hidbuf, embeds, 515);
    run_pass(515, 1024);

    // loss: grid x = row tiles (32 x 64 rows), y = vocab chunks (250)
    k_loss1m<<<dim3(32, NCH), 256, 0, stream>>>(hidbf, embedbf, labels, partm, parts_, llogit);
    k_loss2a<<<(NTOK + 255) / 256, 256, 0, stream>>>(partm, parts_, llogit, nllbuf);
    k_loss2b<<<1, 256, 0, stream>>>(nllbuf, (float*)d_out);
}

// Round 8
// 1263.641 us; speedup vs baseline: 1.0874x; 1.0874x over previous
//
#include <hip/hip_runtime.h>
#include <math.h>

#define B_   2
#define T_   1024
#define D_   1024
#define H_   16
#define DH_  64
#define DFF_ 4096
#define V_   32000
#define NTOK 2046      // B*(T-1)
#define NCH  250       // V_/128 vocab chunks for loss partials

typedef __attribute__((ext_vector_type(8))) short short8;
typedef __attribute__((ext_vector_type(4))) float floatx4;

__device__ __forceinline__ unsigned short f2bf(float x) {
    unsigned int u = __float_as_uint(x);
    unsigned int r = (u + 0x7fffu + ((u >> 16) & 1u)) >> 16;
    return (unsigned short)r;
}

__device__ __forceinline__ float bf2f(unsigned short u) {
    return __uint_as_float((unsigned int)u << 16);
}

__device__ __forceinline__ void gld_lds16(void* lds, const void* g) {
    __builtin_amdgcn_global_load_lds(
        (const __attribute__((address_space(1))) void*)g,
        (__attribute__((address_space(3))) void*)lds, 16, 0, 0);
}

__device__ __forceinline__ float gelu_tanh(float x) {
    float x3 = x * x * x;
    return 0.5f * x * (1.0f + tanhf(0.7978845608028654f * (x + 0.044715f * x3)));
}

// ---------------- weight prep: out[n*K+k] = bf16(W[k*N+n] + 2*(A@Bm)[k,n]) ----------------
__global__ __launch_bounds__(256) void k_prep_w(const float* __restrict__ W,
        const float* __restrict__ A, const float* __restrict__ Bm,
        unsigned short* __restrict__ out, int K, int N, int lora) {
    __shared__ float t[64][65];
    int n0 = blockIdx.x * 64, k0 = blockIdx.y * 64;
    int tid = threadIdx.x;
    int nn = tid & 63, kb = tid >> 6;
    for (int i = 0; i < 16; i++) {
        int kk = kb * 16 + i;
        float v = W[(size_t)(k0 + kk) * N + n0 + nn];
        if (lora) {
            float s = 0.f;
#pragma unroll
            for (int r = 0; r < 8; r++) s += A[(k0 + kk) * 8 + r] * Bm[r * N + n0 + nn];
            v += 2.0f * s;
        }
        t[kk][nn] = v;
    }
    __syncthreads();
    int kk2 = tid & 63, nb = tid >> 6;
    for (int j = 0; j < 16; j++) {
        int nn2 = nb * 16 + j;
        out[(size_t)(n0 + nn2) * K + k0 + kk2] = f2bf(t[kk2][nn2]);
    }
}

// ---------------- fp32 -> bf16 bulk convert ----------------
__global__ void k_f2bf(const float* __restrict__ in, unsigned short* __restrict__ out, int n4) {
    int i = blockIdx.x * 256 + threadIdx.x;
    if (i >= n4) return;
    float4 v = ((const float4*)in)[i];
    ushort4 o;
    o.x = f2bf(v.x); o.y = f2bf(v.y); o.z = f2bf(v.z); o.w = f2bf(v.w);
    ((ushort4*)out)[i] = o;
}

// ---------------- embedding gather ----------------
__global__ void k_embed_gather(const int* __restrict__ ids, const float* __restrict__ embed,
                               float* __restrict__ embeds) {
    int bt = blockIdx.x;
    int d4 = threadIdx.x;
    int id = ids[bt];
    ((float4*)embeds)[(size_t)bt * 256 + d4] = ((const float4*)embed)[(size_t)id * 256 + d4];
}

// ---------------- LayerNorm. If embeds!=null: x = embeds+Wpos (writes hout); else x = in. ----------------
__global__ __launch_bounds__(256) void k_ln(const float* __restrict__ in,
                                            const float* __restrict__ embeds, const float* __restrict__ Wpos,
                                            const float* __restrict__ sc, const float* __restrict__ bi,
                                            float* __restrict__ hout, float* __restrict__ outf,
                                            unsigned short* __restrict__ outbf,
                                            int c0, int range, int strided_bf) {
    int r = blockIdx.x;
    int b = r / range, pos = c0 + r % range;
    size_t rowoff = (size_t)(b * T_ + pos) * D_;
    int tid = threadIdx.x;
    float xv[4];
    if (embeds) {
#pragma unroll
        for (int j = 0; j < 4; j++) {
            int i = tid + j * 256;
            xv[j] = embeds[rowoff + i] + Wpos[(size_t)pos * D_ + i];
            hout[rowoff + i] = xv[j];
        }
    } else {
#pragma unroll
        for (int j = 0; j < 4; j++) xv[j] = in[rowoff + tid + j * 256];
    }
    float s1 = 0.f, s2 = 0.f;
#pragma unroll
    for (int j = 0; j < 4; j++) { s1 += xv[j]; s2 += xv[j] * xv[j]; }
    __shared__ float r1[256], r2[256];
    r1[tid] = s1; r2[tid] = s2; __syncthreads();
    for (int o = 128; o > 0; o >>= 1) {
        if (tid < o) { r1[tid] += r1[tid + o]; r2[tid] += r2[tid + o]; }
        __syncthreads();
    }
    float mean = r1[0] * (1.0f / D_);
    float var = r2[0] * (1.0f / D_) - mean * mean;
    float inv = rsqrtf(var + 1e-5f);
    size_t bfrow = strided_bf ? (size_t)(b * T_ + pos) : (size_t)r;
#pragma unroll
    for (int j = 0; j < 4; j++) {
        int i = tid + j * 256;
        float y = (xv[j] - mean) * inv * sc[i] + bi[i];
        if (outf) outf[rowoff + i] = y;
        outbf[bfrow * D_ + i] = f2bf(y);
    }
}

// ---------------- MFMA GEMM: C[M,N] = A[M,K](bf16) @ Bt[N,K]^T(bf16) ----------------
// 64x128 block tile (r6-proven for pass grids: fills CUs that 128-tiles left idle).
// MODE 1: qkv scatter -> bf16 q / k cache / v cache (u2=vcbf)
// MODE 2: split-K atomic residual add fp32 (grid.z = K segments)
// MODE 3: gelu -> bf16
template <int MODE>
__global__ __launch_bounds__(256) void k_mgemm(const unsigned short* __restrict__ Abf,
        const unsigned short* __restrict__ Bt, const float* __restrict__ bias,
        float* __restrict__ o0, unsigned short* __restrict__ u0,
        unsigned short* __restrict__ u1, unsigned short* __restrict__ u2,
        int M, int N, int K, int c0, int range, int ksegs) {
    __shared__ short8 As_v[256];   // [kg 0..3][row 0..63]
    __shared__ short8 Bs_v[512];   // [kg 0..3][col 0..127]
    int tid = threadIdx.x;
    int lane = tid & 63, w = tid >> 6;
    int quad = lane >> 4, l15 = lane & 15;
    int row0 = blockIdx.y * 64, col0 = blockIdx.x * 128;
    int kseg = blockIdx.z;
    int Klen = K / ksegs;
    int ksoff = kseg * Klen;
    int wr = w >> 1, wc = w & 1;   // wave sub-tile: rows wr*32.., cols wc*64..

    int arow = row0 + lane; if (arow >= M) arow = M - 1;
    const unsigned short* ga  = Abf + (size_t)arow * K + ksoff + w * 8;
    int bcol = col0 + (w & 1) * 64 + lane;
    const unsigned short* gb1 = Bt + (size_t)bcol * K + ksoff + (w >> 1) * 8;
    const unsigned short* gb2 = Bt + (size_t)bcol * K + ksoff + (2 + (w >> 1)) * 8;

    floatx4 acc[2][4];
#pragma unroll
    for (int i = 0; i < 2; i++)
#pragma unroll
        for (int j = 0; j < 4; j++)
#pragma unroll
            for (int k = 0; k < 4; k++) acc[i][j][k] = 0.f;

    int iters = Klen >> 5;
    for (int it = 0; it < iters; ++it) {
        __syncthreads();
        gld_lds16(&As_v[w * 64],        ga);
        gld_lds16(&Bs_v[w * 64],        gb1);
        gld_lds16(&Bs_v[256 + w * 64],  gb2);
        ga += 32; gb1 += 32; gb2 += 32;
        __syncthreads();
        short8 af[2], bfv[4];
#pragma unroll
        for (int mi = 0; mi < 2; mi++) af[mi] = As_v[quad * 64 + wr * 32 + mi * 16 + l15];
#pragma unroll
        for (int nj = 0; nj < 4; nj++) bfv[nj] = Bs_v[quad * 128 + wc * 64 + nj * 16 + l15];
#pragma unroll
        for (int mi = 0; mi < 2; mi++)
#pragma unroll
            for (int nj = 0; nj < 4; nj++)
                acc[mi][nj] = __builtin_amdgcn_mfma_f32_16x16x32_bf16(af[mi], bfv[nj], acc[mi][nj], 0, 0, 0);
    }

#pragma unroll
    for (int mi = 0; mi < 2; mi++)
#pragma unroll
        for (int reg = 0; reg < 4; reg++) {
            int r = row0 + wr * 32 + mi * 16 + quad * 4 + reg;
            if (r >= M) continue;
            int b = r / range, pos = c0 + r % range;
#pragma unroll
            for (int nj = 0; nj < 4; nj++) {
                int n = col0 + wc * 64 + nj * 16 + l15;
                if constexpr (MODE == 1) {
                    float v = acc[mi][nj][reg] + bias[n];
                    if (n < 1024) u0[(size_t)r * 1024 + n] = f2bf(v);
                    else if (n < 2048) u1[(size_t)(b * T_ + pos) * 1024 + (n - 1024)] = f2bf(v);
                    else u2[(size_t)(b * T_ + pos) * 1024 + (n - 2048)] = f2bf(v);
                } else if constexpr (MODE == 2) {
                    float v = acc[mi][nj][reg] + (kseg == 0 ? bias[n] : 0.f);
                    atomicAdd(&o0[(size_t)(b * T_ + pos) * D_ + n], v);
                } else if constexpr (MODE == 3) {
                    float v = acc[mi][nj][reg] + bias[n];
                    u0[(size_t)r * N + n] = f2bf(gelu_tanh(v));
                }
            }
        }
}

// ---------------- small-M (Mr=2) VALU dot GEMM for the range==1 passes ----------------
// MODE 4: qkv scatter (q->u0, k->u1, v DIRECT into transposed vtc u2)
// MODE 2: residual add fp32 into o0
// MODE 3: gelu -> bf16 u0 (rowstride N)
template <int MODE>
__global__ __launch_bounds__(256) void k_sgemm(const unsigned short* __restrict__ Abf,
        const unsigned short* __restrict__ Bt, const float* __restrict__ bias,
        float* __restrict__ o0, unsigned short* __restrict__ u0,
        unsigned short* __restrict__ u1, unsigned short* __restrict__ u2,
        int N, int K, int c0) {
    __shared__ unsigned short lds_a[2 * 4096];   // 2 rows x K (K<=4096), contiguous
    __shared__ float lds_p[4][64][2];
    int tid = threadIdx.x, lane = tid & 63, w = tid >> 6;
    int n = blockIdx.x * 64 + lane;
    // stage A: rows are contiguous (rowstride == K for every caller)
    int nv = (2 * K) >> 3;
    for (int v = tid; v < nv; v += 256)
        *(short8*)&lds_a[v * 8] = *(const short8*)&Abf[v * 8];
    __syncthreads();
    int kq = K >> 2;           // this wave's K-range
    int k0 = w * kq;
    float a0 = 0.f, a1 = 0.f;
    const unsigned short* bp = Bt + (size_t)n * K + k0;
    for (int i = 0; i < kq; i += 8) {
        short8 bv  = *(const short8*)(bp + i);
        short8 av0 = *(const short8*)&lds_a[k0 + i];
        short8 av1 = *(const short8*)&lds_a[K + k0 + i];
#pragma unroll
        for (int j = 0; j < 8; j++) {
            float bf_ = bf2f((unsigned short)bv[j]);
            a0 += bf2f((unsigned short)av0[j]) * bf_;
            a1 += bf2f((unsigned short)av1[j]) * bf_;
        }
    }
    lds_p[w][lane][0] = a0;
    lds_p[w][lane][1] = a1;
    __syncthreads();
    if (tid < 128) {
        int l = tid & 63, m = tid >> 6;          // m = row = batch (range==1)
        int nn = blockIdx.x * 64 + l;
        float acc = lds_p[0][l][m] + lds_p[1][l][m] + lds_p[2][l][m] + lds_p[3][l][m];
        int b = m, pos = c0;
        if constexpr (MODE == 4) {
            float v = acc + bias[nn];
            if (nn < 1024) u0[(size_t)m * 1024 + nn] = f2bf(v);
            else if (nn < 2048) u1[(size_t)(b * T_ + pos) * 1024 + (nn - 1024)] = f2bf(v);
            else {
                int idx = nn - 2048, h = idx >> 6, d = idx & 63;
                u2[(size_t)((b * 16 + h) * 64 + d) * T_ + pos] = f2bf(v);
            }
        } else if constexpr (MODE == 2) {
            o0[(size_t)(b * T_ + pos) * D_ + nn] += acc + bias[nn];
        } else if constexpr (MODE == 3) {
            u0[(size_t)m * N + nn] = f2bf(gelu_tanh(acc + bias[nn]));
        }
    }
}

// ---------------- V transpose into global vtc[(b*16+h)*64+d][T] (big passes) ----------------
__global__ __launch_bounds__(256) void k_vtrans(const unsigned short* __restrict__ vcbf,
        unsigned short* __restrict__ vtc, int c0, int range) {
    __shared__ unsigned short ts[64][72];
    int pt = blockIdx.x, h = blockIdx.y, b = blockIdx.z;
    int t = threadIdx.x;
#pragma unroll
    for (int i = 0; i < 2; i++) {
        int idx = t + i * 256;
        int p = idx >> 3, c8 = idx & 7;
        int pos = c0 + pt * 64 + p;
        if (pos < c0 + range) {
            short8 v = *(const short8*)&vcbf[(size_t)(b * T_ + pos) * D_ + h * 64 + c8 * 8];
            *(short8*)&ts[p][c8 * 8] = v;
        }
    }
    __syncthreads();
#pragma unroll
    for (int i = 0; i < 2; i++) {
        int idx = t + i * 256;
        int d = idx >> 3, p8 = idx & 7;
        unsigned short tmp[8];
#pragma unroll
        for (int j = 0; j < 8; j++) tmp[j] = ts[p8 * 8 + j][d];
        int pos0 = c0 + pt * 64 + p8 * 8;
        size_t rb = (size_t)((b * 16 + h) * 64 + d) * T_;
        if (pos0 + 7 < c0 + range) {
            *(short8*)&vtc[rb + pos0] = *(short8*)tmp;
        } else {
            for (int j = 0; j < 8; j++)
                if (pos0 + j < c0 + range) vtc[rb + pos0 + j] = tmp[j];
        }
    }
}

// ---------------- barrier-free MFMA flash attention ----------------
__global__ __launch_bounds__(256) void k_fattn(const unsigned short* __restrict__ qbf,
        const unsigned short* __restrict__ kcbf, const unsigned short* __restrict__ vtc,
        unsigned short* __restrict__ ctxbf, int c0, int range) {
    __shared__ unsigned short pw[4][16][72];
    int tid = threadIdx.x;
    int w = tid >> 6, lane = tid & 63, quad = lane >> 4, l15 = lane & 15;
    int qt = blockIdx.x, h = blockIdx.y, b = blockIdx.z;
    int q0 = qt * 64 + w * 16;
    if (q0 >= range) return;                 // no barriers in this kernel -> safe
    int qtop = q0 + 15; if (qtop >= range) qtop = range - 1;
    int nkt = (c0 + qtop) / 64 + 1;

    int qrow = q0 + l15; if (qrow >= range) qrow = range - 1;
    const unsigned short* qp = qbf + (size_t)(b * range + qrow) * D_ + h * 64 + quad * 8;
    short8 aq0 = *(const short8*)qp;
    short8 aq1 = *(const short8*)(qp + 32);

    floatx4 oacc[4];
#pragma unroll
    for (int dg = 0; dg < 4; dg++)
#pragma unroll
        for (int r = 0; r < 4; r++) oacc[dg][r] = 0.f;
    float m_r[4] = {-1e30f, -1e30f, -1e30f, -1e30f};
    float l_r[4] = {0.f, 0.f, 0.f, 0.f};

    const unsigned short* kb_p = kcbf + (size_t)b * T_ * D_ + h * 64 + quad * 8;
    const unsigned short* vb_p = vtc + (size_t)((b * 16 + h) * 64 + l15) * T_ + quad * 8;

    for (int kt = 0; kt < nkt; kt++) {
        int kb = kt * 64;
        floatx4 s[4];
#pragma unroll
        for (int g = 0; g < 4; g++) {
            const unsigned short* kp = kb_p + (size_t)(kb + g * 16 + l15) * D_;
            short8 bk0 = *(const short8*)kp;
            short8 bk1 = *(const short8*)(kp + 32);
            floatx4 z; z[0] = 0.f; z[1] = 0.f; z[2] = 0.f; z[3] = 0.f;
            z = __builtin_amdgcn_mfma_f32_16x16x32_bf16(aq0, bk0, z, 0, 0, 0);
            s[g] = __builtin_amdgcn_mfma_f32_16x16x32_bf16(aq1, bk1, z, 0, 0, 0);
        }
#pragma unroll
        for (int r = 0; r < 4; r++) {
            int qpos = c0 + q0 + quad * 4 + r;
            float mx = -1e30f;
#pragma unroll
            for (int g = 0; g < 4; g++) {
                int kpos = kb + g * 16 + l15;
                float sv = (kpos <= qpos) ? s[g][r] * 0.125f : -1e30f;
                s[g][r] = sv; mx = fmaxf(mx, sv);
            }
            mx = fmaxf(mx, __shfl_xor(mx, 1));
            mx = fmaxf(mx, __shfl_xor(mx, 2));
            mx = fmaxf(mx, __shfl_xor(mx, 4));
            mx = fmaxf(mx, __shfl_xor(mx, 8));
            float mn = fmaxf(m_r[r], mx);
            float alpha = __expf(m_r[r] - mn);
            m_r[r] = mn;
            float ls = 0.f;
#pragma unroll
            for (int g = 0; g < 4; g++) {
                float p = __expf(s[g][r] - mn);
                s[g][r] = p; ls += p;
            }
            ls += __shfl_xor(ls, 1);
            ls += __shfl_xor(ls, 2);
            ls += __shfl_xor(ls, 4);
            ls += __shfl_xor(ls, 8);
            l_r[r] = l_r[r] * alpha + ls;
#pragma unroll
            for (int dg = 0; dg < 4; dg++) oacc[dg][r] *= alpha;
        }
#pragma unroll
        for (int g = 0; g < 4; g++)
#pragma unroll
            for (int r = 0; r < 4; r++)
                pw[w][quad * 4 + r][g * 16 + l15] = f2bf(s[g][r]);
        short8 ap0 = *(const short8*)&pw[w][l15][quad * 8];
        short8 ap1 = *(const short8*)&pw[w][l15][32 + quad * 8];
#pragma unroll
        for (int dg = 0; dg < 4; dg++) {
            const unsigned short* vp = vb_p + (size_t)(dg * 16) * T_ + kb;
            short8 bv0 = *(const short8*)vp;
            short8 bv1 = *(const short8*)(vp + 32);
            oacc[dg] = __builtin_amdgcn_mfma_f32_16x16x32_bf16(ap0, bv0, oacc[dg], 0, 0, 0);
            oacc[dg] = __builtin_amdgcn_mfma_f32_16x16x32_bf16(ap1, bv1, oacc[dg], 0, 0, 0);
        }
    }
#pragma unroll
    for (int dg = 0; dg < 4; dg++)
#pragma unroll
        for (int r = 0; r < 4; r++) {
            int qloc = q0 + quad * 4 + r;
            if (qloc < range)
                ctxbf[(size_t)(b * range + qloc) * D_ + h * 64 + dg * 16 + l15] =
                    f2bf(oacc[dg][r] / l_r[r]);
        }
}

// ---------------- latent vec fills ----------------
__global__ void k_latent0(const float* __restrict__ hid, const float* __restrict__ lw,
                          float* __restrict__ embeds) {
    int idx = blockIdx.x * 256 + threadIdx.x;
    if (idx >= B_ * D_) return;
    int b = idx / D_, d = idx % D_;
    float w0 = lw[0], w1 = lw[1], w2 = lw[2];
    float mx = fmaxf(w0, fmaxf(w1, w2));
    float e0 = __expf(w0 - mx), e1 = __expf(w1 - mx), e2 = __expf(w2 - mx);
    float inv = 1.0f / (e0 + e1 + e2);
    float v = (e0 * hid[(size_t)(b * T_ + 509) * D_ + d] +
               e1 * hid[(size_t)(b * T_ + 510) * D_ + d] +
               e2 * hid[(size_t)(b * T_ + 511) * D_ + d]) * inv;
    embeds[(size_t)(b * T_ + 512) * D_ + d] = v;
}

__global__ void k_latent1(const float* __restrict__ hid, float* __restrict__ embeds, int tok) {
    int idx = blockIdx.x * 256 + threadIdx.x;
    if (idx >= B_ * D_) return;
    int b = idx / D_, d = idx % D_;
    embeds[(size_t)(b * T_ + tok) * D_ + d] = hid[(size_t)(b * T_ + tok - 1) * D_ + d];
}

// ---------------- loss MFMA GEMM: r0 128x128 structure + counted-vmcnt pipeline ----------------
// r0 2-barrier loop = 293us, 68% idle at the vmcnt(0) drain (__syncthreads forces
// full drain -> every iteration exposes full load latency). T4 fix: double-buffer
// LDS, issue tile t+1's loads at iter t start, then s_waitcnt vmcnt(4) (wait only
// the OLDER 4 loads) + raw s_barrier -> tile t+1's loads stay in flight through
// the MFMA phase (a full iteration to land). lgkmcnt(0) before the end barrier
// protects the buffer WAR (raw s_barrier doesn't drain ds_reads). Static buffer
// names via unroll-by-2 (rule #20); sched_barrier(0) pins ordering (rule #18).
// Math/fragment map/epilogue byte-identical to the verified r0 kernel.
__global__ __launch_bounds__(256) void k_loss1m(const unsigned short* __restrict__ hidbf,
        const unsigned short* __restrict__ embedbf, const int* __restrict__ labels,
        float* __restrict__ partm, float* __restrict__ parts, float* __restrict__ llogit) {
    __shared__ short8 As0[512], Bs0[512];
    __shared__ short8 As1[512], Bs1[512];
    __shared__ int lds_lab[128];
    __shared__ float lds_pm[128][2];
    __shared__ float lds_ps[128][2];
    int tid = threadIdx.x;
    int lane = tid & 63, w = tid >> 6;
    int quad = lane >> 4, l15 = lane & 15;
    int chunk = blockIdx.y;                     // y = vocab chunk
    int row0 = blockIdx.x * 128, v0 = chunk * 128;
    int rh = (w >> 1) * 64, ch = (w & 1) * 64;

    if (tid < 128) {
        int tok = row0 + tid;
        lds_lab[tid] = (tok < NTOK) ? labels[tok + 1 + (tok >= 1023)] : -1;
    }

    int cA0 = w * 128 + lane, cA1 = cA0 + 64;
    int rA0 = cA0 & 127, kgA0 = cA0 >> 7;
    int rA1 = cA1 & 127, kgA1 = cA1 >> 7;
    int tokA0 = row0 + rA0; if (tokA0 >= NTOK) tokA0 = NTOK - 1;
    int tokA1 = row0 + rA1; if (tokA1 >= NTOK) tokA1 = NTOK - 1;
    const unsigned short* ga0 = hidbf + (size_t)(tokA0 + (tokA0 >= 1023)) * D_ + kgA0 * 8;
    const unsigned short* ga1 = hidbf + (size_t)(tokA1 + (tokA1 >= 1023)) * D_ + kgA1 * 8;
    const unsigned short* gb0 = embedbf + (size_t)(v0 + rA0) * D_ + kgA0 * 8;
    const unsigned short* gb1 = embedbf + (size_t)(v0 + rA1) * D_ + kgA1 * 8;

    floatx4 acc[4][4];
#pragma unroll
    for (int i = 0; i < 4; i++)
#pragma unroll
        for (int j = 0; j < 4; j++)
#pragma unroll
            for (int k = 0; k < 4; k++) acc[i][j][k] = 0.f;

#define LSTAGE(AS, BS) \
    gld_lds16(&AS[w * 128],      ga0); \
    gld_lds16(&AS[w * 128 + 64], ga1); \
    gld_lds16(&BS[w * 128],      gb0); \
    gld_lds16(&BS[w * 128 + 64], gb1); \
    ga0 += 32; ga1 += 32; gb0 += 32; gb1 += 32;

#define LCOMP(AS, BS) { \
    short8 af[4], bfv[4]; \
    _Pragma("unroll") \
    for (int mi = 0; mi < 4; mi++) af[mi] = AS[quad * 128 + rh + mi * 16 + l15]; \
    _Pragma("unroll") \
    for (int nj = 0; nj < 4; nj++) bfv[nj] = BS[quad * 128 + ch + nj * 16 + l15]; \
    _Pragma("unroll") \
    for (int mi = 0; mi < 4; mi++) \
        _Pragma("unroll") \
        for (int nj = 0; nj < 4; nj++) \
            acc[mi][nj] = __builtin_amdgcn_mfma_f32_16x16x32_bf16(af[mi], bfv[nj], acc[mi][nj], 0, 0, 0); }

#define WAIT_VM4_BAR \
    asm volatile("s_waitcnt vmcnt(4)" ::: "memory"); \
    __builtin_amdgcn_s_barrier(); \
    __builtin_amdgcn_sched_barrier(0);

#define WAIT_LGKM_BAR \
    asm volatile("s_waitcnt lgkmcnt(0)" ::: "memory"); \
    __builtin_amdgcn_s_barrier(); \
    __builtin_amdgcn_sched_barrier(0);

    // prologue: tile0 -> buf0 (4 loads in flight)
    LSTAGE(As0, Bs0)
    // main: 15 pairs = iters 0..29 (stage tiles 1..30)
    for (int itp = 0; itp < 15; ++itp) {
        LSTAGE(As1, Bs1)            // tile 2*itp+1 -> buf1 (8 in flight)
        WAIT_VM4_BAR                // tile 2*itp landed everywhere
        LCOMP(As0, Bs0)             // compute tile 2*itp
        WAIT_LGKM_BAR               // all reads of buf0 done -> safe to restage
        LSTAGE(As0, Bs0)            // tile 2*itp+2 -> buf0
        WAIT_VM4_BAR                // tile 2*itp+1 landed
        LCOMP(As1, Bs1)             // compute tile 2*itp+1
        WAIT_LGKM_BAR
    }
    // iter 30: stage tile31 -> buf1, compute tile30 (buf0)
    LSTAGE(As1, Bs1)
    WAIT_VM4_BAR
    LCOMP(As0, Bs0)
    WAIT_LGKM_BAR
    // iter 31: compute tile31 (buf1); only 4 loads outstanding -> drain
    asm volatile("s_waitcnt vmcnt(0)" ::: "memory");
    __builtin_amdgcn_s_barrier();
    __builtin_amdgcn_sched_barrier(0);
    LCOMP(As1, Bs1)

#undef LSTAGE
#undef LCOMP
#undef WAIT_VM4_BAR
#undef WAIT_LGKM_BAR

#pragma unroll
    for (int mi = 0; mi < 4; mi++)
#pragma unroll
        for (int reg = 0; reg < 4; reg++) {
            int rloc = rh + mi * 16 + quad * 4 + reg;
            int lab = lds_lab[rloc];
            float vm = -1e30f;
#pragma unroll
            for (int nj = 0; nj < 4; nj++) {
                float v = acc[mi][nj][reg];
                int vcol = v0 + ch + nj * 16 + l15;
                if (vcol == lab) llogit[row0 + rloc] = v;
                vm = fmaxf(vm, v);
            }
            for (int off = 1; off < 16; off <<= 1) vm = fmaxf(vm, __shfl_xor(vm, off));
            float ss = 0.f;
#pragma unroll
            for (int nj = 0; nj < 4; nj++) ss += __expf(acc[mi][nj][reg] - vm);
            for (int off = 1; off < 16; off <<= 1) ss += __shfl_xor(ss, off);
            if (l15 == 0) { lds_pm[rloc][ch >> 6] = vm; lds_ps[rloc][ch >> 6] = ss; }
        }
    __syncthreads();
    if (tid < 128) {
        int tok = row0 + tid;
        if (tok < NTOK) {
            float m0 = lds_pm[tid][0], m1 = lds_pm[tid][1];
            float M = fmaxf(m0, m1);
            float S = lds_ps[tid][0] * __expf(m0 - M) + lds_ps[tid][1] * __expf(m1 - M);
            partm[(size_t)chunk * NTOK + tok] = M;
            parts[(size_t)chunk * NTOK + tok] = S;
        }
    }
}

// ---------------- loss combine ----------------
__global__ void k_loss2a(const float* __restrict__ partm, const float* __restrict__ parts,
                         const float* __restrict__ ll, float* __restrict__ nll) {
    int tok = blockIdx.x * 256 + threadIdx.x;
    if (tok >= NTOK) return;
    float M = -1e30f;
    for (int c = 0; c < NCH; c++) M = fmaxf(M, partm[(size_t)c * NTOK + tok]);
    float S = 0.f;
    for (int c = 0; c < NCH; c++)
        S += parts[(size_t)c * NTOK + tok] * __expf(partm[(size_t)c * NTOK + tok] - M);
    nll[tok] = logf(S) + M - ll[tok];
}

__global__ __launch_bounds__(256) void k_loss2b(const float* __restrict__ nll, float* __restrict__ out) {
    __shared__ float red[256];
    int tid = threadIdx.x;
    float s = 0.f;
    for (int i = tid; i < NTOK; i += 256) s += nll[i];
    red[tid] = s; __syncthreads();
    for (int o = 128; o > 0; o >>= 1) {
        if (tid < o) red[tid] += red[tid + o];
        __syncthreads();
    }
    if (tid == 0) out[0] = red[0] / (float)NTOK;
}

// ---------------- host ----------------
extern "C" void kernel_launch(void* const* d_in, const int* in_sizes, int n_in,
                              void* d_out, int out_size, void* d_ws, size_t ws_size,
                              hipStream_t stream) {
    const int*   input_ids = (const int*)d_in[0];
    const int*   labels    = (const int*)d_in[2];
    const float* embed     = (const float*)d_in[4];
    const float* Wpos      = (const float*)d_in[5];
    const float* Wqkv      = (const float*)d_in[6];
    const float* bqkv      = (const float*)d_in[7];
    const float* Aq        = (const float*)d_in[8];
    const float* Bq        = (const float*)d_in[9];
    const float* Wo        = (const float*)d_in[10];
    const float* bo        = (const float*)d_in[11];
    const float* Ao        = (const float*)d_in[12];
    const float* Bo        = (const float*)d_in[13];
    const float* W1        = (const float*)d_in[14];
    const float* b1        = (const float*)d_in[15];
    const float* W2        = (const float*)d_in[16];
    const float* b2        = (const float*)d_in[17];
    const float* ln1_s     = (const float*)d_in[18];
    const float* ln1_b     = (const float*)d_in[19];
    const float* ln2_s     = (const float*)d_in[20];
    const float* ln2_b     = (const float*)d_in[21];
    const float* lnf_s     = (const float*)d_in[22];
    const float* lnf_b     = (const float*)d_in[23];
    const float* latent_w  = (const float*)d_in[24];

    char* base = (char*)d_ws;
    size_t off = 0;
    auto alloc = [&](size_t bytes) { void* p = base + off; off += (bytes + 255) & ~255ULL; return p; };

    float* embeds  = (float*)alloc((size_t)B_ * T_ * D_ * 4);
    float* hbuf    = (float*)alloc((size_t)B_ * T_ * D_ * 4);
    float* hidbuf  = (float*)alloc((size_t)B_ * T_ * D_ * 4);
    float* partm   = (float*)alloc((size_t)NCH * NTOK * 4);
    float* parts_  = (float*)alloc((size_t)NCH * NTOK * 4);
    float* llogit  = (float*)alloc((size_t)NTOK * 4);
    float* nllbuf  = (float*)alloc((size_t)NTOK * 4);
    unsigned short* wqkvT  = (unsigned short*)alloc((size_t)3072 * 1024 * 2);
    unsigned short* woT    = (unsigned short*)alloc((size_t)1024 * 1024 * 2);
    unsigned short* W1T    = (unsigned short*)alloc((size_t)4096 * 1024 * 2);
    unsigned short* W2T    = (unsigned short*)alloc((size_t)1024 * 4096 * 2);
    unsigned short* embedbf = (unsigned short*)alloc((size_t)V_ * D_ * 2);
    unsigned short* hidbf  = (unsigned short*)alloc((size_t)B_ * T_ * D_ * 2);
    unsigned short* abf    = (unsigned short*)alloc((size_t)1024 * D_ * 2);
    unsigned short* ctxbf  = (unsigned short*)alloc((size_t)1024 * D_ * 2);
    unsigned short* ffbw   = (unsigned short*)alloc((size_t)1024 * DFF_ * 2);
    unsigned short* qbf    = (unsigned short*)alloc((size_t)1024 * D_ * 2);
    unsigned short* kcbf   = (unsigned short*)alloc((size_t)B_ * T_ * D_ * 2);
    unsigned short* vcbf   = (unsigned short*)alloc((size_t)B_ * T_ * D_ * 2);
    unsigned short* vtc    = (unsigned short*)alloc((size_t)B_ * H_ * DH_ * T_ * 2);

    // weight prep (transpose + LoRA merge + bf16)
    k_prep_w<<<dim3(3072 / 64, 1024 / 64), 256, 0, stream>>>(Wqkv, Aq, Bq, wqkvT, 1024, 3072, 1);
    k_prep_w<<<dim3(1024 / 64, 1024 / 64), 256, 0, stream>>>(Wo, Ao, Bo, woT, 1024, 1024, 1);
    k_prep_w<<<dim3(4096 / 64, 1024 / 64), 256, 0, stream>>>(W1, nullptr, nullptr, W1T, 1024, 4096, 0);
    k_prep_w<<<dim3(1024 / 64, 4096 / 64), 256, 0, stream>>>(W2, nullptr, nullptr, W2T, 4096, 1024, 0);
    k_f2bf<<<(V_ * D_ / 4 + 255) / 256, 256, 0, stream>>>(embed, embedbf, V_ * D_ / 4);
    k_embed_gather<<<B_ * T_, 256, 0, stream>>>(input_ids, embed, embeds);

    auto run_pass = [&](int c0, int c1) {
        int range = c1 - c0;
        int Mr = B_ * range;
        int gy = (Mr + 63) / 64;
        int qt = (range + 63) / 64;
        // ln1 (fused h = embeds + Wpos -> hbuf)
        k_ln<<<Mr, 256, 0, stream>>>(nullptr, embeds, Wpos, ln1_s, ln1_b, hbuf, nullptr, abf, c0, range, 0);
        if (range == 1) {
            // small-M path: VALU dot kernels, v scattered directly into vtc
            k_sgemm<4><<<3072 / 64, 256, 0, stream>>>(abf, wqkvT, bqkv, nullptr, qbf, kcbf, vtc,
                                                      3072, 1024, c0);
            k_fattn<<<dim3(1, H_, B_), 256, 0, stream>>>(qbf, kcbf, vtc, ctxbf, c0, 1);
            k_sgemm<2><<<1024 / 64, 256, 0, stream>>>(ctxbf, woT, bo, hbuf, nullptr, nullptr, nullptr,
                                                      1024, 1024, c0);
            k_ln<<<Mr, 256, 0, stream>>>(hbuf, nullptr, nullptr, ln2_s, ln2_b, nullptr, nullptr, abf, c0, range, 0);
            k_sgemm<3><<<4096 / 64, 256, 0, stream>>>(abf, W1T, b1, nullptr, ffbw, nullptr, nullptr,
                                                      4096, 1024, c0);
            k_sgemm<2><<<1024 / 64, 256, 0, stream>>>(ffbw, W2T, b2, hbuf, nullptr, nullptr, nullptr,
                                                      1024, 4096, c0);
        } else {
            k_mgemm<1><<<dim3(3072 / 128, gy), 256, 0, stream>>>(abf, wqkvT, bqkv, nullptr, qbf, kcbf, vcbf,
                                                                 Mr, 3072, 1024, c0, range, 1);
            k_vtrans<<<dim3(qt, H_, B_), 256, 0, stream>>>(vcbf, vtc, c0, range);
            k_fattn<<<dim3(qt, H_, B_), 256, 0, stream>>>(qbf, kcbf, vtc, ctxbf, c0, range);
            k_mgemm<2><<<dim3(1024 / 128, gy, 4), 256, 0, stream>>>(ctxbf, woT, bo, hbuf, nullptr, nullptr, nullptr,
                                                                    Mr, 1024, 1024, c0, range, 4);
            k_ln<<<Mr, 256, 0, stream>>>(hbuf, nullptr, nullptr, ln2_s, ln2_b, nullptr, nullptr, abf, c0, range, 0);
            k_mgemm<3><<<dim3(4096 / 128, gy), 256, 0, stream>>>(abf, W1T, b1, nullptr, ffbw, nullptr, nullptr,
                                                                 Mr, 4096, 1024, c0, range, 1);
            k_mgemm<2><<<dim3(1024 / 128, gy, 4), 256, 0, stream>>>(ffbw, W2T, b2, hbuf, nullptr, nullptr, nullptr,
                                                                    Mr, 1024, 4096, c0, range, 4);
        }
        k_ln<<<Mr, 256, 0, stream>>>(hbuf, nullptr, nullptr, lnf_s, lnf_b, nullptr, hidbuf, hidbf, c0, range, 1);
    };

    run_pass(0, 512);
    k_latent0<<<(B_ * D_ + 255) / 256, 256, 0, stream>>>(hidbuf, latent_w, embeds);
    run_pass(512, 513);
    k_latent1<<<(B_ * D_ + 255) / 256, 256, 0, stream>>>(hidbuf, embeds, 513);
    run_pass(513, 514);
    k_latent1<<<(B_ * D_ + 255) / 256, 256, 0, stream>>>(hidbuf, embeds, 514);
    run_pass(514, 515);
    k_latent1<<<(B_ * D_ + 255) / 256, 256, 0, stream>>>(hidbuf, embeds, 515);
    run_pass(515, 1024);

    // loss: grid x = row tiles (16), y = vocab chunks (250) for L2 reuse of embed slices
    k_loss1m<<<dim3((NTOK + 127) / 128, NCH), 256, 0, stream>>>(hidbf, embedbf, labels, partm, parts_, llogit);
    k_loss2a<<<(NTOK + 255) / 256, 256, 0, stream>>>(partm, parts_, llogit, nllbuf);
    k_loss2b<<<1, 256, 0, stream>>>(nllbuf, (float*)d_out);
}

// Round 9
// 1172.989 us; speedup vs baseline: 1.1714x; 1.0773x over previous
//
#include <hip/hip_runtime.h>
#include <math.h>

#define B_   2
#define T_   1024
#define D_   1024
#define H_   16
#define DH_  64
#define DFF_ 4096
#define V_   32000
#define NTOK 2046      // B*(T-1)
#define NCH  250       // V_/128 vocab chunks for loss partials

typedef __attribute__((ext_vector_type(8))) short short8;
typedef __attribute__((ext_vector_type(4))) float floatx4;

__device__ __forceinline__ unsigned short f2bf(float x) {
    unsigned int u = __float_as_uint(x);
    unsigned int r = (u + 0x7fffu + ((u >> 16) & 1u)) >> 16;
    return (unsigned short)r;
}

__device__ __forceinline__ float bf2f(unsigned short u) {
    return __uint_as_float((unsigned int)u << 16);
}

__device__ __forceinline__ void gld_lds16(void* lds, const void* g) {
    __builtin_amdgcn_global_load_lds(
        (const __attribute__((address_space(1))) void*)g,
        (__attribute__((address_space(3))) void*)lds, 16, 0, 0);
}

__device__ __forceinline__ float gelu_tanh(float x) {
    float x3 = x * x * x;
    return 0.5f * x * (1.0f + tanhf(0.7978845608028654f * (x + 0.044715f * x3)));
}

// ---------------- weight prep: out[n*K+k] = bf16(W[k*N+n] + 2*(A@Bm)[k,n]) ----------------
__global__ __launch_bounds__(256) void k_prep_w(const float* __restrict__ W,
        const float* __restrict__ A, const float* __restrict__ Bm,
        unsigned short* __restrict__ out, int K, int N, int lora) {
    __shared__ float t[64][65];
    int n0 = blockIdx.x * 64, k0 = blockIdx.y * 64;
    int tid = threadIdx.x;
    int nn = tid & 63, kb = tid >> 6;
    for (int i = 0; i < 16; i++) {
        int kk = kb * 16 + i;
        float v = W[(size_t)(k0 + kk) * N + n0 + nn];
        if (lora) {
            float s = 0.f;
#pragma unroll
            for (int r = 0; r < 8; r++) s += A[(k0 + kk) * 8 + r] * Bm[r * N + n0 + nn];
            v += 2.0f * s;
        }
        t[kk][nn] = v;
    }
    __syncthreads();
    int kk2 = tid & 63, nb = tid >> 6;
    for (int j = 0; j < 16; j++) {
        int nn2 = nb * 16 + j;
        out[(size_t)(n0 + nn2) * K + k0 + kk2] = f2bf(t[kk2][nn2]);
    }
}

// ---------------- fp32 -> bf16 bulk convert ----------------
__global__ void k_f2bf(const float* __restrict__ in, unsigned short* __restrict__ out, int n4) {
    int i = blockIdx.x * 256 + threadIdx.x;
    if (i >= n4) return;
    float4 v = ((const float4*)in)[i];
    ushort4 o;
    o.x = f2bf(v.x); o.y = f2bf(v.y); o.z = f2bf(v.z); o.w = f2bf(v.w);
    ((ushort4*)out)[i] = o;
}

// ---------------- embedding gather ----------------
__global__ void k_embed_gather(const int* __restrict__ ids, const float* __restrict__ embed,
                               float* __restrict__ embeds) {
    int bt = blockIdx.x;
    int d4 = threadIdx.x;
    int id = ids[bt];
    ((float4*)embeds)[(size_t)bt * 256 + d4] = ((const float4*)embed)[(size_t)id * 256 + d4];
}

// ---------------- LayerNorm. If embeds!=null: x = embeds+Wpos (writes hout); else x = in. ----------------
__global__ __launch_bounds__(256) void k_ln(const float* __restrict__ in,
                                            const float* __restrict__ embeds, const float* __restrict__ Wpos,
                                            const float* __restrict__ sc, const float* __restrict__ bi,
                                            float* __restrict__ hout, float* __restrict__ outf,
                                            unsigned short* __restrict__ outbf,
                                            int c0, int range, int strided_bf) {
    int r = blockIdx.x;
    int b = r / range, pos = c0 + r % range;
    size_t rowoff = (size_t)(b * T_ + pos) * D_;
    int tid = threadIdx.x;
    float xv[4];
    if (embeds) {
#pragma unroll
        for (int j = 0; j < 4; j++) {
            int i = tid + j * 256;
            xv[j] = embeds[rowoff + i] + Wpos[(size_t)pos * D_ + i];
            hout[rowoff + i] = xv[j];
        }
    } else {
#pragma unroll
        for (int j = 0; j < 4; j++) xv[j] = in[rowoff + tid + j * 256];
    }
    float s1 = 0.f, s2 = 0.f;
#pragma unroll
    for (int j = 0; j < 4; j++) { s1 += xv[j]; s2 += xv[j] * xv[j]; }
    __shared__ float r1[256], r2[256];
    r1[tid] = s1; r2[tid] = s2; __syncthreads();
    for (int o = 128; o > 0; o >>= 1) {
        if (tid < o) { r1[tid] += r1[tid + o]; r2[tid] += r2[tid + o]; }
        __syncthreads();
    }
    float mean = r1[0] * (1.0f / D_);
    float var = r2[0] * (1.0f / D_) - mean * mean;
    float inv = rsqrtf(var + 1e-5f);
    size_t bfrow = strided_bf ? (size_t)(b * T_ + pos) : (size_t)r;
#pragma unroll
    for (int j = 0; j < 4; j++) {
        int i = tid + j * 256;
        float y = (xv[j] - mean) * inv * sc[i] + bi[i];
        if (outf) outf[rowoff + i] = y;
        outbf[bfrow * D_ + i] = f2bf(y);
    }
}

// ---------------- MFMA GEMM: C[M,N] = A[M,K](bf16) @ Bt[N,K]^T(bf16) ----------------
// 64x128 tile (r6-proven) + r8-verified counted-vmcnt 2-deep pipeline:
// double-buffer LDS, stage tile t+1 before waiting, s_waitcnt vmcnt(3)
// (3 loads/wave/stage) + raw barrier -> next tile's loads stay in flight
// through the MFMA phase. lgkmcnt(0)+barrier protects buffer WAR.
// MODE 1: qkv scatter -> bf16 q / k cache / v cache (u2=vcbf)
// MODE 2: split-K atomic residual add fp32 (grid.z = K segments)
// MODE 3: gelu -> bf16
template <int MODE>
__global__ __launch_bounds__(256) void k_mgemm(const unsigned short* __restrict__ Abf,
        const unsigned short* __restrict__ Bt, const float* __restrict__ bias,
        float* __restrict__ o0, unsigned short* __restrict__ u0,
        unsigned short* __restrict__ u1, unsigned short* __restrict__ u2,
        int M, int N, int K, int c0, int range, int ksegs) {
    __shared__ short8 As0[256], Bs0[512];
    __shared__ short8 As1[256], Bs1[512];
    int tid = threadIdx.x;
    int lane = tid & 63, w = tid >> 6;
    int quad = lane >> 4, l15 = lane & 15;
    int row0 = blockIdx.y * 64, col0 = blockIdx.x * 128;
    int kseg = blockIdx.z;
    int Klen = K / ksegs;
    int ksoff = kseg * Klen;
    int wr = w >> 1, wc = w & 1;   // wave sub-tile: rows wr*32.., cols wc*64..

    int arow = row0 + lane; if (arow >= M) arow = M - 1;
    const unsigned short* ga  = Abf + (size_t)arow * K + ksoff + w * 8;
    int bcol = col0 + (w & 1) * 64 + lane;
    const unsigned short* gb1 = Bt + (size_t)bcol * K + ksoff + (w >> 1) * 8;
    const unsigned short* gb2 = Bt + (size_t)bcol * K + ksoff + (2 + (w >> 1)) * 8;

    floatx4 acc[2][4];
#pragma unroll
    for (int i = 0; i < 2; i++)
#pragma unroll
        for (int j = 0; j < 4; j++)
#pragma unroll
            for (int k = 0; k < 4; k++) acc[i][j][k] = 0.f;

    int iters = Klen >> 5;   // always even (>=8) for all callers

#define MSTAGE(AS, BS) \
    gld_lds16(&AS[w * 64],       ga); \
    gld_lds16(&BS[w * 64],       gb1); \
    gld_lds16(&BS[256 + w * 64], gb2); \
    ga += 32; gb1 += 32; gb2 += 32;

#define MCOMP(AS, BS) { \
    short8 af[2], bfv[4]; \
    _Pragma("unroll") \
    for (int mi = 0; mi < 2; mi++) af[mi] = AS[quad * 64 + wr * 32 + mi * 16 + l15]; \
    _Pragma("unroll") \
    for (int nj = 0; nj < 4; nj++) bfv[nj] = BS[quad * 128 + wc * 64 + nj * 16 + l15]; \
    _Pragma("unroll") \
    for (int mi = 0; mi < 2; mi++) \
        _Pragma("unroll") \
        for (int nj = 0; nj < 4; nj++) \
            acc[mi][nj] = __builtin_amdgcn_mfma_f32_16x16x32_bf16(af[mi], bfv[nj], acc[mi][nj], 0, 0, 0); }

#define MWVM3 \
    asm volatile("s_waitcnt vmcnt(3)" ::: "memory"); \
    __builtin_amdgcn_s_barrier(); \
    __builtin_amdgcn_sched_barrier(0);

#define MWLG \
    asm volatile("s_waitcnt lgkmcnt(0)" ::: "memory"); \
    __builtin_amdgcn_s_barrier(); \
    __builtin_amdgcn_sched_barrier(0);

    MSTAGE(As0, Bs0)                         // tile 0 (3 in flight)
    for (int itp = 0; itp < (iters >> 1) - 1; ++itp) {
        MSTAGE(As1, Bs1) MWVM3 MCOMP(As0, Bs0) MWLG
        MSTAGE(As0, Bs0) MWVM3 MCOMP(As1, Bs1) MWLG
    }
    MSTAGE(As1, Bs1) MWVM3 MCOMP(As0, Bs0) MWLG
    asm volatile("s_waitcnt vmcnt(0)" ::: "memory");
    __builtin_amdgcn_s_barrier();
    __builtin_amdgcn_sched_barrier(0);
    MCOMP(As1, Bs1)

#undef MSTAGE
#undef MCOMP
#undef MWVM3
#undef MWLG

#pragma unroll
    for (int mi = 0; mi < 2; mi++)
#pragma unroll
        for (int reg = 0; reg < 4; reg++) {
            int r = row0 + wr * 32 + mi * 16 + quad * 4 + reg;
            if (r >= M) continue;
            int b = r / range, pos = c0 + r % range;
#pragma unroll
            for (int nj = 0; nj < 4; nj++) {
                int n = col0 + wc * 64 + nj * 16 + l15;
                if constexpr (MODE == 1) {
                    float v = acc[mi][nj][reg] + bias[n];
                    if (n < 1024) u0[(size_t)r * 1024 + n] = f2bf(v);
                    else if (n < 2048) u1[(size_t)(b * T_ + pos) * 1024 + (n - 1024)] = f2bf(v);
                    else u2[(size_t)(b * T_ + pos) * 1024 + (n - 2048)] = f2bf(v);
                } else if constexpr (MODE == 2) {
                    float v = acc[mi][nj][reg] + (kseg == 0 ? bias[n] : 0.f);
                    atomicAdd(&o0[(size_t)(b * T_ + pos) * D_ + n], v);
                } else if constexpr (MODE == 3) {
                    float v = acc[mi][nj][reg] + bias[n];
                    u0[(size_t)r * N + n] = f2bf(gelu_tanh(v));
                }
            }
        }
}

// ---------------- tiny-pass (Mr=2) GEMV, cross-block K-split ----------------
// Old k_sgemm used 16-64 blocks to stream MB-scale weights (6% of CUs for
// W2T's 8 MB). Now: grid = (N/64) x (K/256); each block computes a 256-wide
// K-slice partial for 64 cols x 2 rows. k_sp_part writes DETERMINISTIC
// partials pacc[kseg][m][N] (no atomics/memset; finisher sums + activates).
// k_sp_add (residual path) atomicAdds partials directly into fp32 o0.
__global__ __launch_bounds__(256) void k_sp_part(const unsigned short* __restrict__ Abf,
        const unsigned short* __restrict__ Bt, float* __restrict__ pacc, int N, int K) {
    __shared__ unsigned short lds_a[2][256];
    __shared__ float lds_p[4][64][2];
    int tid = threadIdx.x, lane = tid & 63, w = tid >> 6;
    int n = blockIdx.x * 64 + lane;
    int kseg = blockIdx.y, k0 = kseg * 256;
    if (tid < 64) {
        int m = tid >> 5, j = tid & 31;
        *(short8*)&lds_a[m][j * 8] = *(const short8*)&Abf[(size_t)m * K + k0 + j * 8];
    }
    __syncthreads();
    int kw = w * 64;
    float a0 = 0.f, a1 = 0.f;
    const unsigned short* bp = Bt + (size_t)n * K + k0 + kw;
#pragma unroll
    for (int i = 0; i < 64; i += 8) {
        short8 bv  = *(const short8*)(bp + i);
        short8 av0 = *(const short8*)&lds_a[0][kw + i];
        short8 av1 = *(const short8*)&lds_a[1][kw + i];
#pragma unroll
        for (int j = 0; j < 8; j++) {
            float bf_ = bf2f((unsigned short)bv[j]);
            a0 += bf2f((unsigned short)av0[j]) * bf_;
            a1 += bf2f((unsigned short)av1[j]) * bf_;
        }
    }
    lds_p[w][lane][0] = a0;
    lds_p[w][lane][1] = a1;
    __syncthreads();
    if (tid < 128) {
        int l = tid & 63, m = tid >> 6;
        int nn = blockIdx.x * 64 + l;
        float acc = lds_p[0][l][m] + lds_p[1][l][m] + lds_p[2][l][m] + lds_p[3][l][m];
        pacc[((size_t)kseg * 2 + m) * N + nn] = acc;
    }
}

// residual path: atomic partials straight into fp32 o0 (bias added by kseg 0)
__global__ __launch_bounds__(256) void k_sp_add(const unsigned short* __restrict__ Abf,
        const unsigned short* __restrict__ Bt, const float* __restrict__ bias,
        float* __restrict__ o0, int N, int K, int c0) {
    __shared__ unsigned short lds_a[2][256];
    __shared__ float lds_p[4][64][2];
    int tid = threadIdx.x, lane = tid & 63, w = tid >> 6;
    int n = blockIdx.x * 64 + lane;
    int kseg = blockIdx.y, k0 = kseg * 256;
    if (tid < 64) {
        int m = tid >> 5, j = tid & 31;
        *(short8*)&lds_a[m][j * 8] = *(const short8*)&Abf[(size_t)m * K + k0 + j * 8];
    }
    __syncthreads();
    int kw = w * 64;
    float a0 = 0.f, a1 = 0.f;
    const unsigned short* bp = Bt + (size_t)n * K + k0 + kw;
#pragma unroll
    for (int i = 0; i < 64; i += 8) {
        short8 bv  = *(const short8*)(bp + i);
        short8 av0 = *(const short8*)&lds_a[0][kw + i];
        short8 av1 = *(const short8*)&lds_a[1][kw + i];
#pragma unroll
        for (int j = 0; j < 8; j++) {
            float bf_ = bf2f((unsigned short)bv[j]);
            a0 += bf2f((unsigned short)av0[j]) * bf_;
            a1 += bf2f((unsigned short)av1[j]) * bf_;
        }
    }
    lds_p[w][lane][0] = a0;
    lds_p[w][lane][1] = a1;
    __syncthreads();
    if (tid < 128) {
        int l = tid & 63, m = tid >> 6;
        int nn = blockIdx.x * 64 + l;
        float acc = lds_p[0][l][m] + lds_p[1][l][m] + lds_p[2][l][m] + lds_p[3][l][m];
        if (kseg == 0) acc += bias[nn];
        atomicAdd(&o0[(size_t)(m * T_ + c0) * D_ + nn], acc);
    }
}

// finisher: sum nseg partials, bias, activation/scatter.
// MODE 4: qkv scatter (q->u0, k->u1, v DIRECT into transposed vtc u2)
// MODE 3: gelu -> bf16 u0 (rowstride N)
template <int MODE>
__global__ void k_sp_fin(const float* __restrict__ pacc, const float* __restrict__ bias,
        unsigned short* __restrict__ u0, unsigned short* __restrict__ u1,
        unsigned short* __restrict__ u2, int N, int nseg, int c0) {
    int idx = blockIdx.x * 256 + threadIdx.x;
    if (idx >= 2 * N) return;
    int m = idx / N, n = idx % N;
    float s = 0.f;
    for (int k = 0; k < nseg; k++) s += pacc[((size_t)k * 2 + m) * N + n];
    s += bias[n];
    if constexpr (MODE == 4) {
        if (n < 1024) u0[(size_t)m * 1024 + n] = f2bf(s);
        else if (n < 2048) u1[(size_t)(m * T_ + c0) * 1024 + (n - 1024)] = f2bf(s);
        else {
            int id2 = n - 2048, h = id2 >> 6, d = id2 & 63;
            u2[(size_t)((m * 16 + h) * 64 + d) * T_ + c0] = f2bf(s);
        }
    } else {
        u0[(size_t)m * N + n] = f2bf(gelu_tanh(s));
    }
}

// ---------------- V transpose into global vtc[(b*16+h)*64+d][T] (big passes) ----------------
__global__ __launch_bounds__(256) void k_vtrans(const unsigned short* __restrict__ vcbf,
        unsigned short* __restrict__ vtc, int c0, int range) {
    __shared__ unsigned short ts[64][72];
    int pt = blockIdx.x, h = blockIdx.y, b = blockIdx.z;
    int t = threadIdx.x;
#pragma unroll
    for (int i = 0; i < 2; i++) {
        int idx = t + i * 256;
        int p = idx >> 3, c8 = idx & 7;
        int pos = c0 + pt * 64 + p;
        if (pos < c0 + range) {
            short8 v = *(const short8*)&vcbf[(size_t)(b * T_ + pos) * D_ + h * 64 + c8 * 8];
            *(short8*)&ts[p][c8 * 8] = v;
        }
    }
    __syncthreads();
#pragma unroll
    for (int i = 0; i < 2; i++) {
        int idx = t + i * 256;
        int d = idx >> 3, p8 = idx & 7;
        unsigned short tmp[8];
#pragma unroll
        for (int j = 0; j < 8; j++) tmp[j] = ts[p8 * 8 + j][d];
        int pos0 = c0 + pt * 64 + p8 * 8;
        size_t rb = (size_t)((b * 16 + h) * 64 + d) * T_;
        if (pos0 + 7 < c0 + range) {
            *(short8*)&vtc[rb + pos0] = *(short8*)tmp;
        } else {
            for (int j = 0; j < 8; j++)
                if (pos0 + j < c0 + range) vtc[rb + pos0 + j] = tmp[j];
        }
    }
}

// ---------------- barrier-free MFMA flash attention ----------------
__global__ __launch_bounds__(256) void k_fattn(const unsigned short* __restrict__ qbf,
        const unsigned short* __restrict__ kcbf, const unsigned short* __restrict__ vtc,
        unsigned short* __restrict__ ctxbf, int c0, int range) {
    __shared__ unsigned short pw[4][16][72];
    int tid = threadIdx.x;
    int w = tid >> 6, lane = tid & 63, quad = lane >> 4, l15 = lane & 15;
    int qt = blockIdx.x, h = blockIdx.y, b = blockIdx.z;
    int q0 = qt * 64 + w * 16;
    if (q0 >= range) return;                 // no barriers in this kernel -> safe
    int qtop = q0 + 15; if (qtop >= range) qtop = range - 1;
    int nkt = (c0 + qtop) / 64 + 1;

    int qrow = q0 + l15; if (qrow >= range) qrow = range - 1;
    const unsigned short* qp = qbf + (size_t)(b * range + qrow) * D_ + h * 64 + quad * 8;
    short8 aq0 = *(const short8*)qp;
    short8 aq1 = *(const short8*)(qp + 32);

    floatx4 oacc[4];
#pragma unroll
    for (int dg = 0; dg < 4; dg++)
#pragma unroll
        for (int r = 0; r < 4; r++) oacc[dg][r] = 0.f;
    float m_r[4] = {-1e30f, -1e30f, -1e30f, -1e30f};
    float l_r[4] = {0.f, 0.f, 0.f, 0.f};

    const unsigned short* kb_p = kcbf + (size_t)b * T_ * D_ + h * 64 + quad * 8;
    const unsigned short* vb_p = vtc + (size_t)((b * 16 + h) * 64 + l15) * T_ + quad * 8;

    for (int kt = 0; kt < nkt; kt++) {
        int kb = kt * 64;
        floatx4 s[4];
#pragma unroll
        for (int g = 0; g < 4; g++) {
            const unsigned short* kp = kb_p + (size_t)(kb + g * 16 + l15) * D_;
            short8 bk0 = *(const short8*)kp;
            short8 bk1 = *(const short8*)(kp + 32);
            floatx4 z; z[0] = 0.f; z[1] = 0.f; z[2] = 0.f; z[3] = 0.f;
            z = __builtin_amdgcn_mfma_f32_16x16x32_bf16(aq0, bk0, z, 0, 0, 0);
            s[g] = __builtin_amdgcn_mfma_f32_16x16x32_bf16(aq1, bk1, z, 0, 0, 0);
        }
#pragma unroll
        for (int r = 0; r < 4; r++) {
            int qpos = c0 + q0 + quad * 4 + r;
            float mx = -1e30f;
#pragma unroll
            for (int g = 0; g < 4; g++) {
                int kpos = kb + g * 16 + l15;
                float sv = (kpos <= qpos) ? s[g][r] * 0.125f : -1e30f;
                s[g][r] = sv; mx = fmaxf(mx, sv);
            }
            mx = fmaxf(mx, __shfl_xor(mx, 1));
            mx = fmaxf(mx, __shfl_xor(mx, 2));
            mx = fmaxf(mx, __shfl_xor(mx, 4));
            mx = fmaxf(mx, __shfl_xor(mx, 8));
            float mn = fmaxf(m_r[r], mx);
            float alpha = __expf(m_r[r] - mn);
            m_r[r] = mn;
            float ls = 0.f;
#pragma unroll
            for (int g = 0; g < 4; g++) {
                float p = __expf(s[g][r] - mn);
                s[g][r] = p; ls += p;
            }
            ls += __shfl_xor(ls, 1);
            ls += __shfl_xor(ls, 2);
            ls += __shfl_xor(ls, 4);
            ls += __shfl_xor(ls, 8);
            l_r[r] = l_r[r] * alpha + ls;
#pragma unroll
            for (int dg = 0; dg < 4; dg++) oacc[dg][r] *= alpha;
        }
#pragma unroll
        for (int g = 0; g < 4; g++)
#pragma unroll
            for (int r = 0; r < 4; r++)
                pw[w][quad * 4 + r][g * 16 + l15] = f2bf(s[g][r]);
        short8 ap0 = *(const short8*)&pw[w][l15][quad * 8];
        short8 ap1 = *(const short8*)&pw[w][l15][32 + quad * 8];
#pragma unroll
        for (int dg = 0; dg < 4; dg++) {
            const unsigned short* vp = vb_p + (size_t)(dg * 16) * T_ + kb;
            short8 bv0 = *(const short8*)vp;
            short8 bv1 = *(const short8*)(vp + 32);
            oacc[dg] = __builtin_amdgcn_mfma_f32_16x16x32_bf16(ap0, bv0, oacc[dg], 0, 0, 0);
            oacc[dg] = __builtin_amdgcn_mfma_f32_16x16x32_bf16(ap1, bv1, oacc[dg], 0, 0, 0);
        }
    }
#pragma unroll
    for (int dg = 0; dg < 4; dg++)
#pragma unroll
        for (int r = 0; r < 4; r++) {
            int qloc = q0 + quad * 4 + r;
            if (qloc < range)
                ctxbf[(size_t)(b * range + qloc) * D_ + h * 64 + dg * 16 + l15] =
                    f2bf(oacc[dg][r] / l_r[r]);
        }
}

// ---------------- latent vec fills ----------------
__global__ void k_latent0(const float* __restrict__ hid, const float* __restrict__ lw,
                          float* __restrict__ embeds) {
    int idx = blockIdx.x * 256 + threadIdx.x;
    if (idx >= B_ * D_) return;
    int b = idx / D_, d = idx % D_;
    float w0 = lw[0], w1 = lw[1], w2 = lw[2];
    float mx = fmaxf(w0, fmaxf(w1, w2));
    float e0 = __expf(w0 - mx), e1 = __expf(w1 - mx), e2 = __expf(w2 - mx);
    float inv = 1.0f / (e0 + e1 + e2);
    float v = (e0 * hid[(size_t)(b * T_ + 509) * D_ + d] +
               e1 * hid[(size_t)(b * T_ + 510) * D_ + d] +
               e2 * hid[(size_t)(b * T_ + 511) * D_ + d]) * inv;
    embeds[(size_t)(b * T_ + 512) * D_ + d] = v;
}

__global__ void k_latent1(const float* __restrict__ hid, float* __restrict__ embeds, int tok) {
    int idx = blockIdx.x * 256 + threadIdx.x;
    if (idx >= B_ * D_) return;
    int b = idx / D_, d = idx % D_;
    embeds[(size_t)(b * T_ + tok) * D_ + d] = hid[(size_t)(b * T_ + tok - 1) * D_ + d];
}

// ---------------- loss MFMA GEMM: r8-verified counted-vmcnt pipeline (280us) ----------------
__global__ __launch_bounds__(256) void k_loss1m(const unsigned short* __restrict__ hidbf,
        const unsigned short* __restrict__ embedbf, const int* __restrict__ labels,
        float* __restrict__ partm, float* __restrict__ parts, float* __restrict__ llogit) {
    __shared__ short8 As0[512], Bs0[512];
    __shared__ short8 As1[512], Bs1[512];
    __shared__ int lds_lab[128];
    __shared__ float lds_pm[128][2];
    __shared__ float lds_ps[128][2];
    int tid = threadIdx.x;
    int lane = tid & 63, w = tid >> 6;
    int quad = lane >> 4, l15 = lane & 15;
    int chunk = blockIdx.y;                     // y = vocab chunk
    int row0 = blockIdx.x * 128, v0 = chunk * 128;
    int rh = (w >> 1) * 64, ch = (w & 1) * 64;

    if (tid < 128) {
        int tok = row0 + tid;
        lds_lab[tid] = (tok < NTOK) ? labels[tok + 1 + (tok >= 1023)] : -1;
    }

    int cA0 = w * 128 + lane, cA1 = cA0 + 64;
    int rA0 = cA0 & 127, kgA0 = cA0 >> 7;
    int rA1 = cA1 & 127, kgA1 = cA1 >> 7;
    int tokA0 = row0 + rA0; if (tokA0 >= NTOK) tokA0 = NTOK - 1;
    int tokA1 = row0 + rA1; if (tokA1 >= NTOK) tokA1 = NTOK - 1;
    const unsigned short* ga0 = hidbf + (size_t)(tokA0 + (tokA0 >= 1023)) * D_ + kgA0 * 8;
    const unsigned short* ga1 = hidbf + (size_t)(tokA1 + (tokA1 >= 1023)) * D_ + kgA1 * 8;
    const unsigned short* gb0 = embedbf + (size_t)(v0 + rA0) * D_ + kgA0 * 8;
    const unsigned short* gb1 = embedbf + (size_t)(v0 + rA1) * D_ + kgA1 * 8;

    floatx4 acc[4][4];
#pragma unroll
    for (int i = 0; i < 4; i++)
#pragma unroll
        for (int j = 0; j < 4; j++)
#pragma unroll
            for (int k = 0; k < 4; k++) acc[i][j][k] = 0.f;

#define LSTAGE(AS, BS) \
    gld_lds16(&AS[w * 128],      ga0); \
    gld_lds16(&AS[w * 128 + 64], ga1); \
    gld_lds16(&BS[w * 128],      gb0); \
    gld_lds16(&BS[w * 128 + 64], gb1); \
    ga0 += 32; ga1 += 32; gb0 += 32; gb1 += 32;

#define LCOMP(AS, BS) { \
    short8 af[4], bfv[4]; \
    _Pragma("unroll") \
    for (int mi = 0; mi < 4; mi++) af[mi] = AS[quad * 128 + rh + mi * 16 + l15]; \
    _Pragma("unroll") \
    for (int nj = 0; nj < 4; nj++) bfv[nj] = BS[quad * 128 + ch + nj * 16 + l15]; \
    _Pragma("unroll") \
    for (int mi = 0; mi < 4; mi++) \
        _Pragma("unroll") \
        for (int nj = 0; nj < 4; nj++) \
            acc[mi][nj] = __builtin_amdgcn_mfma_f32_16x16x32_bf16(af[mi], bfv[nj], acc[mi][nj], 0, 0, 0); }

#define WAIT_VM4_BAR \
    asm volatile("s_waitcnt vmcnt(4)" ::: "memory"); \
    __builtin_amdgcn_s_barrier(); \
    __builtin_amdgcn_sched_barrier(0);

#define WAIT_LGKM_BAR \
    asm volatile("s_waitcnt lgkmcnt(0)" ::: "memory"); \
    __builtin_amdgcn_s_barrier(); \
    __builtin_amdgcn_sched_barrier(0);

    // prologue: tile0 -> buf0 (4 loads in flight)
    LSTAGE(As0, Bs0)
    // main: 15 pairs = iters 0..29 (stage tiles 1..30)
    for (int itp = 0; itp < 15; ++itp) {
        LSTAGE(As1, Bs1)            // tile 2*itp+1 -> buf1 (8 in flight)
        WAIT_VM4_BAR                // tile 2*itp landed everywhere
        LCOMP(As0, Bs0)             // compute tile 2*itp
        WAIT_LGKM_BAR               // all reads of buf0 done -> safe to restage
        LSTAGE(As0, Bs0)            // tile 2*itp+2 -> buf0
        WAIT_VM4_BAR                // tile 2*itp+1 landed
        LCOMP(As1, Bs1)             // compute tile 2*itp+1
        WAIT_LGKM_BAR
    }
    // iter 30: stage tile31 -> buf1, compute tile30 (buf0)
    LSTAGE(As1, Bs1)
    WAIT_VM4_BAR
    LCOMP(As0, Bs0)
    WAIT_LGKM_BAR
    // iter 31: compute tile31 (buf1); only 4 loads outstanding -> drain
    asm volatile("s_waitcnt vmcnt(0)" ::: "memory");
    __builtin_amdgcn_s_barrier();
    __builtin_amdgcn_sched_barrier(0);
    LCOMP(As1, Bs1)

#undef LSTAGE
#undef LCOMP
#undef WAIT_VM4_BAR
#undef WAIT_LGKM_BAR

#pragma unroll
    for (int mi = 0; mi < 4; mi++)
#pragma unroll
        for (int reg = 0; reg < 4; reg++) {
            int rloc = rh + mi * 16 + quad * 4 + reg;
            int lab = lds_lab[rloc];
            float vm = -1e30f;
#pragma unroll
            for (int nj = 0; nj < 4; nj++) {
                float v = acc[mi][nj][reg];
                int vcol = v0 + ch + nj * 16 + l15;
                if (vcol == lab) llogit[row0 + rloc] = v;
                vm = fmaxf(vm, v);
            }
            for (int off = 1; off < 16; off <<= 1) vm = fmaxf(vm, __shfl_xor(vm, off));
            float ss = 0.f;
#pragma unroll
            for (int nj = 0; nj < 4; nj++) ss += __expf(acc[mi][nj][reg] - vm);
            for (int off = 1; off < 16; off <<= 1) ss += __shfl_xor(ss, off);
            if (l15 == 0) { lds_pm[rloc][ch >> 6] = vm; lds_ps[rloc][ch >> 6] = ss; }
        }
    __syncthreads();
    if (tid < 128) {
        int tok = row0 + tid;
        if (tok < NTOK) {
            float m0 = lds_pm[tid][0], m1 = lds_pm[tid][1];
            float M = fmaxf(m0, m1);
            float S = lds_ps[tid][0] * __expf(m0 - M) + lds_ps[tid][1] * __expf(m1 - M);
            partm[(size_t)chunk * NTOK + tok] = M;
            parts[(size_t)chunk * NTOK + tok] = S;
        }
    }
}

// ---------------- loss combine ----------------
__global__ void k_loss2a(const float* __restrict__ partm, const float* __restrict__ parts,
                         const float* __restrict__ ll, float* __restrict__ nll) {
    int tok = blockIdx.x * 256 + threadIdx.x;
    if (tok >= NTOK) return;
    float M = -1e30f;
    for (int c = 0; c < NCH; c++) M = fmaxf(M, partm[(size_t)c * NTOK + tok]);
    float S = 0.f;
    for (int c = 0; c < NCH; c++)
        S += parts[(size_t)c * NTOK + tok] * __expf(partm[(size_t)c * NTOK + tok] - M);
    nll[tok] = logf(S) + M - ll[tok];
}

__global__ __launch_bounds__(256) void k_loss2b(const float* __restrict__ nll, float* __restrict__ out) {
    __shared__ float red[256];
    int tid = threadIdx.x;
    float s = 0.f;
    for (int i = tid; i < NTOK; i += 256) s += nll[i];
    red[tid] = s; __syncthreads();
    for (int o = 128; o > 0; o >>= 1) {
        if (tid < o) red[tid] += red[tid + o];
        __syncthreads();
    }
    if (tid == 0) out[0] = red[0] / (float)NTOK;
}

// ---------------- host ----------------
extern "C" void kernel_launch(void* const* d_in, const int* in_sizes, int n_in,
                              void* d_out, int out_size, void* d_ws, size_t ws_size,
                              hipStream_t stream) {
    const int*   input_ids = (const int*)d_in[0];
    const int*   labels    = (const int*)d_in[2];
    const float* embed     = (const float*)d_in[4];
    const float* Wpos      = (const float*)d_in[5];
    const float* Wqkv      = (const float*)d_in[6];
    const float* bqkv      = (const float*)d_in[7];
    const float* Aq        = (const float*)d_in[8];
    const float* Bq        = (const float*)d_in[9];
    const float* Wo        = (const float*)d_in[10];
    const float* bo        = (const float*)d_in[11];
    const float* Ao        = (const float*)d_in[12];
    const float* Bo        = (const float*)d_in[13];
    const float* W1        = (const float*)d_in[14];
    const float* b1        = (const float*)d_in[15];
    const float* W2        = (const float*)d_in[16];
    const float* b2        = (const float*)d_in[17];
    const float* ln1_s     = (const float*)d_in[18];
    const float* ln1_b     = (const float*)d_in[19];
    const float* ln2_s     = (const float*)d_in[20];
    const float* ln2_b     = (const float*)d_in[21];
    const float* lnf_s     = (const float*)d_in[22];
    const float* lnf_b     = (const float*)d_in[23];
    const float* latent_w  = (const float*)d_in[24];

    char* base = (char*)d_ws;
    size_t off = 0;
    auto alloc = [&](size_t bytes) { void* p = base + off; off += (bytes + 255) & ~255ULL; return p; };

    float* embeds  = (float*)alloc((size_t)B_ * T_ * D_ * 4);
    float* hbuf    = (float*)alloc((size_t)B_ * T_ * D_ * 4);
    float* hidbuf  = (float*)alloc((size_t)B_ * T_ * D_ * 4);
    float* partm   = (float*)alloc((size_t)NCH * NTOK * 4);
    float* parts_  = (float*)alloc((size_t)NCH * NTOK * 4);
    float* llogit  = (float*)alloc((size_t)NTOK * 4);
    float* nllbuf  = (float*)alloc((size_t)NTOK * 4);
    float* pacc    = (float*)alloc((size_t)16 * 2 * 4096 * 4);   // tiny-pass partials
    unsigned short* wqkvT  = (unsigned short*)alloc((size_t)3072 * 1024 * 2);
    unsigned short* woT    = (unsigned short*)alloc((size_t)1024 * 1024 * 2);
    unsigned short* W1T    = (unsigned short*)alloc((size_t)4096 * 1024 * 2);
    unsigned short* W2T    = (unsigned short*)alloc((size_t)1024 * 4096 * 2);
    unsigned short* embedbf = (unsigned short*)alloc((size_t)V_ * D_ * 2);
    unsigned short* hidbf  = (unsigned short*)alloc((size_t)B_ * T_ * D_ * 2);
    unsigned short* abf    = (unsigned short*)alloc((size_t)1024 * D_ * 2);
    unsigned short* ctxbf  = (unsigned short*)alloc((size_t)1024 * D_ * 2);
    unsigned short* ffbw   = (unsigned short*)alloc((size_t)1024 * DFF_ * 2);
    unsigned short* qbf    = (unsigned short*)alloc((size_t)1024 * D_ * 2);
    unsigned short* kcbf   = (unsigned short*)alloc((size_t)B_ * T_ * D_ * 2);
    unsigned short* vcbf   = (unsigned short*)alloc((size_t)B_ * T_ * D_ * 2);
    unsigned short* vtc    = (unsigned short*)alloc((size_t)B_ * H_ * DH_ * T_ * 2);

    // weight prep (transpose + LoRA merge + bf16)
    k_prep_w<<<dim3(3072 / 64, 1024 / 64), 256, 0, stream>>>(Wqkv, Aq, Bq, wqkvT, 1024, 3072, 1);
    k_prep_w<<<dim3(1024 / 64, 1024 / 64), 256, 0, stream>>>(Wo, Ao, Bo, woT, 1024, 1024, 1);
    k_prep_w<<<dim3(4096 / 64, 1024 / 64), 256, 0, stream>>>(W1, nullptr, nullptr, W1T, 1024, 4096, 0);
    k_prep_w<<<dim3(1024 / 64, 4096 / 64), 256, 0, stream>>>(W2, nullptr, nullptr, W2T, 4096, 1024, 0);
    k_f2bf<<<(V_ * D_ / 4 + 255) / 256, 256, 0, stream>>>(embed, embedbf, V_ * D_ / 4);
    k_embed_gather<<<B_ * T_, 256, 0, stream>>>(input_ids, embed, embeds);

    auto run_pass = [&](int c0, int c1) {
        int range = c1 - c0;
        int Mr = B_ * range;
        int gy = (Mr + 63) / 64;
        int qt = (range + 63) / 64;
        // ln1 (fused h = embeds + Wpos -> hbuf)
        k_ln<<<Mr, 256, 0, stream>>>(nullptr, embeds, Wpos, ln1_s, ln1_b, hbuf, nullptr, abf, c0, range, 0);
        if (range == 1) {
            // tiny pass: chip-wide K-split GEMVs (grid = cols/64 x K/256)
            k_sp_part<<<dim3(48, 4), 256, 0, stream>>>(abf, wqkvT, pacc, 3072, 1024);
            k_sp_fin<4><<<24, 256, 0, stream>>>(pacc, bqkv, qbf, kcbf, vtc, 3072, 4, c0);
            k_fattn<<<dim3(1, H_, B_), 256, 0, stream>>>(qbf, kcbf, vtc, ctxbf, c0, 1);
            k_sp_add<<<dim3(16, 4), 256, 0, stream>>>(ctxbf, woT, bo, hbuf, 1024, 1024, c0);
            k_ln<<<Mr, 256, 0, stream>>>(hbuf, nullptr, nullptr, ln2_s, ln2_b, nullptr, nullptr, abf, c0, range, 0);
            k_sp_part<<<dim3(64, 4), 256, 0, stream>>>(abf, W1T, pacc, 4096, 1024);
            k_sp_fin<3><<<32, 256, 0, stream>>>(pacc, b1, ffbw, nullptr, nullptr, 4096, 4, c0);
            k_sp_add<<<dim3(16, 16), 256, 0, stream>>>(ffbw, W2T, b2, hbuf, 1024, 4096, c0);
        } else {
            k_mgemm<1><<<dim3(3072 / 128, gy), 256, 0, stream>>>(abf, wqkvT, bqkv, nullptr, qbf, kcbf, vcbf,
                                                                 Mr, 3072, 1024, c0, range, 1);
            k_vtrans<<<dim3(qt, H_, B_), 256, 0, stream>>>(vcbf, vtc, c0, range);
            k_fattn<<<dim3(qt, H_, B_), 256, 0, stream>>>(qbf, kcbf, vtc, ctxbf, c0, range);
            k_mgemm<2><<<dim3(1024 / 128, gy, 4), 256, 0, stream>>>(ctxbf, woT, bo, hbuf, nullptr, nullptr, nullptr,
                                                                    Mr, 1024, 1024, c0, range, 4);
            k_ln<<<Mr, 256, 0, stream>>>(hbuf, nullptr, nullptr, ln2_s, ln2_b, nullptr, nullptr, abf, c0, range, 0);
            k_mgemm<3><<<dim3(4096 / 128, gy), 256, 0, stream>>>(abf, W1T, b1, nullptr, ffbw, nullptr, nullptr,
                                                                 Mr, 4096, 1024, c0, range, 1);
            k_mgemm<2><<<dim3(1024 / 128, gy, 4), 256, 0, stream>>>(ffbw, W2T, b2, hbuf, nullptr, nullptr, nullptr,
                                                                    Mr, 1024, 4096, c0, range, 4);
        }
        k_ln<<<Mr, 256, 0, stream>>>(hbuf, nullptr, nullptr, lnf_s, lnf_b, nullptr, hidbuf, hidbf, c0, range, 1);
    };

    run_pass(0, 512);
    k_latent0<<<(B_ * D_ + 255) / 256, 256, 0, stream>>>(hidbuf, latent_w, embeds);
    run_pass(512, 513);
    k_latent1<<<(B_ * D_ + 255) / 256, 256, 0, stream>>>(hidbuf, embeds, 513);
    run_pass(513, 514);
    k_latent1<<<(B_ * D_ + 255) / 256, 256, 0, stream>>>(hidbuf, embeds, 514);
    run_pass(514, 515);
    k_latent1<<<(B_ * D_ + 255) / 256, 256, 0, stream>>>(hidbuf, embeds, 515);
    run_pass(515, 1024);

    // loss: grid x = row tiles (16), y = vocab chunks (250) for L2 reuse of embed slices
    k_loss1m<<<dim3((NTOK + 127) / 128, NCH), 256, 0, stream>>>(hidbf, embedbf, labels, partm, parts_, llogit);
    k_loss2a<<<(NTOK + 255) / 256, 256, 0, stream>>>(partm, parts_, llogit, nllbuf);
    k_loss2b<<<1, 256, 0, stream>>>(nllbuf, (float*)d_out);
}

// Round 10
// 1130.146 us; speedup vs baseline: 1.2158x; 1.0379x over previous
//
#include <hip/hip_runtime.h>
#include <math.h>

#define B_   2
#define T_   1024
#define D_   1024
#define H_   16
#define DH_  64
#define DFF_ 4096
#define V_   32000
#define NTOK 2046      // B*(T-1)
#define NCH  125       // V_/256 vocab chunks for loss partials (256-col chunks)

typedef __attribute__((ext_vector_type(8))) short short8;
typedef __attribute__((ext_vector_type(4))) float floatx4;

__device__ __forceinline__ unsigned short f2bf(float x) {
    unsigned int u = __float_as_uint(x);
    unsigned int r = (u + 0x7fffu + ((u >> 16) & 1u)) >> 16;
    return (unsigned short)r;
}

__device__ __forceinline__ float bf2f(unsigned short u) {
    return __uint_as_float((unsigned int)u << 16);
}

__device__ __forceinline__ void gld_lds16(void* lds, const void* g) {
    __builtin_amdgcn_global_load_lds(
        (const __attribute__((address_space(1))) void*)g,
        (__attribute__((address_space(3))) void*)lds, 16, 0, 0);
}

__device__ __forceinline__ float gelu_tanh(float x) {
    float x3 = x * x * x;
    return 0.5f * x * (1.0f + tanhf(0.7978845608028654f * (x + 0.044715f * x3)));
}

// ---------------- weight prep: out[n*K+k] = bf16(W[k*N+n] + 2*(A@Bm)[k,n]) ----------------
__global__ __launch_bounds__(256) void k_prep_w(const float* __restrict__ W,
        const float* __restrict__ A, const float* __restrict__ Bm,
        unsigned short* __restrict__ out, int K, int N, int lora) {
    __shared__ float t[64][65];
    int n0 = blockIdx.x * 64, k0 = blockIdx.y * 64;
    int tid = threadIdx.x;
    int nn = tid & 63, kb = tid >> 6;
    for (int i = 0; i < 16; i++) {
        int kk = kb * 16 + i;
        float v = W[(size_t)(k0 + kk) * N + n0 + nn];
        if (lora) {
            float s = 0.f;
#pragma unroll
            for (int r = 0; r < 8; r++) s += A[(k0 + kk) * 8 + r] * Bm[r * N + n0 + nn];
            v += 2.0f * s;
        }
        t[kk][nn] = v;
    }
    __syncthreads();
    int kk2 = tid & 63, nb = tid >> 6;
    for (int j = 0; j < 16; j++) {
        int nn2 = nb * 16 + j;
        out[(size_t)(n0 + nn2) * K + k0 + kk2] = f2bf(t[kk2][nn2]);
    }
}

// ---------------- fp32 -> bf16 bulk convert ----------------
__global__ void k_f2bf(const float* __restrict__ in, unsigned short* __restrict__ out, int n4) {
    int i = blockIdx.x * 256 + threadIdx.x;
    if (i >= n4) return;
    float4 v = ((const float4*)in)[i];
    ushort4 o;
    o.x = f2bf(v.x); o.y = f2bf(v.y); o.z = f2bf(v.z); o.w = f2bf(v.w);
    ((ushort4*)out)[i] = o;
}

// ---------------- embedding gather ----------------
__global__ void k_embed_gather(const int* __restrict__ ids, const float* __restrict__ embed,
                               float* __restrict__ embeds) {
    int bt = blockIdx.x;
    int d4 = threadIdx.x;
    int id = ids[bt];
    ((float4*)embeds)[(size_t)bt * 256 + d4] = ((const float4*)embed)[(size_t)id * 256 + d4];
}

// ---------------- LayerNorm. If embeds!=null: x = embeds+Wpos (writes hout); else x = in. ----------------
__global__ __launch_bounds__(256) void k_ln(const float* __restrict__ in,
                                            const float* __restrict__ embeds, const float* __restrict__ Wpos,
                                            const float* __restrict__ sc, const float* __restrict__ bi,
                                            float* __restrict__ hout, float* __restrict__ outf,
                                            unsigned short* __restrict__ outbf,
                                            int c0, int range, int strided_bf) {
    int r = blockIdx.x;
    int b = r / range, pos = c0 + r % range;
    size_t rowoff = (size_t)(b * T_ + pos) * D_;
    int tid = threadIdx.x;
    float xv[4];
    if (embeds) {
#pragma unroll
        for (int j = 0; j < 4; j++) {
            int i = tid + j * 256;
            xv[j] = embeds[rowoff + i] + Wpos[(size_t)pos * D_ + i];
            hout[rowoff + i] = xv[j];
        }
    } else {
#pragma unroll
        for (int j = 0; j < 4; j++) xv[j] = in[rowoff + tid + j * 256];
    }
    float s1 = 0.f, s2 = 0.f;
#pragma unroll
    for (int j = 0; j < 4; j++) { s1 += xv[j]; s2 += xv[j] * xv[j]; }
    __shared__ float r1[256], r2[256];
    r1[tid] = s1; r2[tid] = s2; __syncthreads();
    for (int o = 128; o > 0; o >>= 1) {
        if (tid < o) { r1[tid] += r1[tid + o]; r2[tid] += r2[tid + o]; }
        __syncthreads();
    }
    float mean = r1[0] * (1.0f / D_);
    float var = r2[0] * (1.0f / D_) - mean * mean;
    float inv = rsqrtf(var + 1e-5f);
    size_t bfrow = strided_bf ? (size_t)(b * T_ + pos) : (size_t)r;
#pragma unroll
    for (int j = 0; j < 4; j++) {
        int i = tid + j * 256;
        float y = (xv[j] - mean) * inv * sc[i] + bi[i];
        if (outf) outf[rowoff + i] = y;
        outbf[bfrow * D_ + i] = f2bf(y);
    }
}

// ---------------- MFMA GEMM: C[M,N] = A[M,K](bf16) @ Bt[N,K]^T(bf16) ----------------
// 64x128 tile (r6-proven) + r8-verified counted-vmcnt 2-deep pipeline.
// MODE 1: qkv scatter -> bf16 q / k cache / v cache (u2=vcbf)
// MODE 2: split-K atomic residual add fp32 (grid.z = K segments)
// MODE 3: gelu -> bf16
template <int MODE>
__global__ __launch_bounds__(256) void k_mgemm(const unsigned short* __restrict__ Abf,
        const unsigned short* __restrict__ Bt, const float* __restrict__ bias,
        float* __restrict__ o0, unsigned short* __restrict__ u0,
        unsigned short* __restrict__ u1, unsigned short* __restrict__ u2,
        int M, int N, int K, int c0, int range, int ksegs) {
    __shared__ short8 As0[256], Bs0[512];
    __shared__ short8 As1[256], Bs1[512];
    int tid = threadIdx.x;
    int lane = tid & 63, w = tid >> 6;
    int quad = lane >> 4, l15 = lane & 15;
    int row0 = blockIdx.y * 64, col0 = blockIdx.x * 128;
    int kseg = blockIdx.z;
    int Klen = K / ksegs;
    int ksoff = kseg * Klen;
    int wr = w >> 1, wc = w & 1;   // wave sub-tile: rows wr*32.., cols wc*64..

    int arow = row0 + lane; if (arow >= M) arow = M - 1;
    const unsigned short* ga  = Abf + (size_t)arow * K + ksoff + w * 8;
    int bcol = col0 + (w & 1) * 64 + lane;
    const unsigned short* gb1 = Bt + (size_t)bcol * K + ksoff + (w >> 1) * 8;
    const unsigned short* gb2 = Bt + (size_t)bcol * K + ksoff + (2 + (w >> 1)) * 8;

    floatx4 acc[2][4];
#pragma unroll
    for (int i = 0; i < 2; i++)
#pragma unroll
        for (int j = 0; j < 4; j++)
#pragma unroll
            for (int k = 0; k < 4; k++) acc[i][j][k] = 0.f;

    int iters = Klen >> 5;   // always even (>=8) for all callers

#define MSTAGE(AS, BS) \
    gld_lds16(&AS[w * 64],       ga); \
    gld_lds16(&BS[w * 64],       gb1); \
    gld_lds16(&BS[256 + w * 64], gb2); \
    ga += 32; gb1 += 32; gb2 += 32;

#define MCOMP(AS, BS) { \
    short8 af[2], bfv[4]; \
    _Pragma("unroll") \
    for (int mi = 0; mi < 2; mi++) af[mi] = AS[quad * 64 + wr * 32 + mi * 16 + l15]; \
    _Pragma("unroll") \
    for (int nj = 0; nj < 4; nj++) bfv[nj] = BS[quad * 128 + wc * 64 + nj * 16 + l15]; \
    _Pragma("unroll") \
    for (int mi = 0; mi < 2; mi++) \
        _Pragma("unroll") \
        for (int nj = 0; nj < 4; nj++) \
            acc[mi][nj] = __builtin_amdgcn_mfma_f32_16x16x32_bf16(af[mi], bfv[nj], acc[mi][nj], 0, 0, 0); }

#define MWVM3 \
    asm volatile("s_waitcnt vmcnt(3)" ::: "memory"); \
    __builtin_amdgcn_s_barrier(); \
    __builtin_amdgcn_sched_barrier(0);

#define MWLG \
    asm volatile("s_waitcnt lgkmcnt(0)" ::: "memory"); \
    __builtin_amdgcn_s_barrier(); \
    __builtin_amdgcn_sched_barrier(0);

    MSTAGE(As0, Bs0)                         // tile 0 (3 in flight)
    for (int itp = 0; itp < (iters >> 1) - 1; ++itp) {
        MSTAGE(As1, Bs1) MWVM3 MCOMP(As0, Bs0) MWLG
        MSTAGE(As0, Bs0) MWVM3 MCOMP(As1, Bs1) MWLG
    }
    MSTAGE(As1, Bs1) MWVM3 MCOMP(As0, Bs0) MWLG
    asm volatile("s_waitcnt vmcnt(0)" ::: "memory");
    __builtin_amdgcn_s_barrier();
    __builtin_amdgcn_sched_barrier(0);
    MCOMP(As1, Bs1)

#undef MSTAGE
#undef MCOMP
#undef MWVM3
#undef MWLG

#pragma unroll
    for (int mi = 0; mi < 2; mi++)
#pragma unroll
        for (int reg = 0; reg < 4; reg++) {
            int r = row0 + wr * 32 + mi * 16 + quad * 4 + reg;
            if (r >= M) continue;
            int b = r / range, pos = c0 + r % range;
#pragma unroll
            for (int nj = 0; nj < 4; nj++) {
                int n = col0 + wc * 64 + nj * 16 + l15;
                if constexpr (MODE == 1) {
                    float v = acc[mi][nj][reg] + bias[n];
                    if (n < 1024) u0[(size_t)r * 1024 + n] = f2bf(v);
                    else if (n < 2048) u1[(size_t)(b * T_ + pos) * 1024 + (n - 1024)] = f2bf(v);
                    else u2[(size_t)(b * T_ + pos) * 1024 + (n - 2048)] = f2bf(v);
                } else if constexpr (MODE == 2) {
                    float v = acc[mi][nj][reg] + (kseg == 0 ? bias[n] : 0.f);
                    atomicAdd(&o0[(size_t)(b * T_ + pos) * D_ + n], v);
                } else if constexpr (MODE == 3) {
                    float v = acc[mi][nj][reg] + bias[n];
                    u0[(size_t)r * N + n] = f2bf(gelu_tanh(v));
                }
            }
        }
}

// ---------------- tiny-pass (Mr=2) GEMV, cross-block K-split (r9-verified) ----------------
__global__ __launch_bounds__(256) void k_sp_part(const unsigned short* __restrict__ Abf,
        const unsigned short* __restrict__ Bt, float* __restrict__ pacc, int N, int K) {
    __shared__ unsigned short lds_a[2][256];
    __shared__ float lds_p[4][64][2];
    int tid = threadIdx.x, lane = tid & 63, w = tid >> 6;
    int n = blockIdx.x * 64 + lane;
    int kseg = blockIdx.y, k0 = kseg * 256;
    if (tid < 64) {
        int m = tid >> 5, j = tid & 31;
        *(short8*)&lds_a[m][j * 8] = *(const short8*)&Abf[(size_t)m * K + k0 + j * 8];
    }
    __syncthreads();
    int kw = w * 64;
    float a0 = 0.f, a1 = 0.f;
    const unsigned short* bp = Bt + (size_t)n * K + k0 + kw;
#pragma unroll
    for (int i = 0; i < 64; i += 8) {
        short8 bv  = *(const short8*)(bp + i);
        short8 av0 = *(const short8*)&lds_a[0][kw + i];
        short8 av1 = *(const short8*)&lds_a[1][kw + i];
#pragma unroll
        for (int j = 0; j < 8; j++) {
            float bf_ = bf2f((unsigned short)bv[j]);
            a0 += bf2f((unsigned short)av0[j]) * bf_;
            a1 += bf2f((unsigned short)av1[j]) * bf_;
        }
    }
    lds_p[w][lane][0] = a0;
    lds_p[w][lane][1] = a1;
    __syncthreads();
    if (tid < 128) {
        int l = tid & 63, m = tid >> 6;
        int nn = blockIdx.x * 64 + l;
        float acc = lds_p[0][l][m] + lds_p[1][l][m] + lds_p[2][l][m] + lds_p[3][l][m];
        pacc[((size_t)kseg * 2 + m) * N + nn] = acc;
    }
}

__global__ __launch_bounds__(256) void k_sp_add(const unsigned short* __restrict__ Abf,
        const unsigned short* __restrict__ Bt, const float* __restrict__ bias,
        float* __restrict__ o0, int N, int K, int c0) {
    __shared__ unsigned short lds_a[2][256];
    __shared__ float lds_p[4][64][2];
    int tid = threadIdx.x, lane = tid & 63, w = tid >> 6;
    int n = blockIdx.x * 64 + lane;
    int kseg = blockIdx.y, k0 = kseg * 256;
    if (tid < 64) {
        int m = tid >> 5, j = tid & 31;
        *(short8*)&lds_a[m][j * 8] = *(const short8*)&Abf[(size_t)m * K + k0 + j * 8];
    }
    __syncthreads();
    int kw = w * 64;
    float a0 = 0.f, a1 = 0.f;
    const unsigned short* bp = Bt + (size_t)n * K + k0 + kw;
#pragma unroll
    for (int i = 0; i < 64; i += 8) {
        short8 bv  = *(const short8*)(bp + i);
        short8 av0 = *(const short8*)&lds_a[0][kw + i];
        short8 av1 = *(const short8*)&lds_a[1][kw + i];
#pragma unroll
        for (int j = 0; j < 8; j++) {
            float bf_ = bf2f((unsigned short)bv[j]);
            a0 += bf2f((unsigned short)av0[j]) * bf_;
            a1 += bf2f((unsigned short)av1[j]) * bf_;
        }
    }
    lds_p[w][lane][0] = a0;
    lds_p[w][lane][1] = a1;
    __syncthreads();
    if (tid < 128) {
        int l = tid & 63, m = tid >> 6;
        int nn = blockIdx.x * 64 + l;
        float acc = lds_p[0][l][m] + lds_p[1][l][m] + lds_p[2][l][m] + lds_p[3][l][m];
        if (kseg == 0) acc += bias[nn];
        atomicAdd(&o0[(size_t)(m * T_ + c0) * D_ + nn], acc);
    }
}

template <int MODE>
__global__ void k_sp_fin(const float* __restrict__ pacc, const float* __restrict__ bias,
        unsigned short* __restrict__ u0, unsigned short* __restrict__ u1,
        unsigned short* __restrict__ u2, int N, int nseg, int c0) {
    int idx = blockIdx.x * 256 + threadIdx.x;
    if (idx >= 2 * N) return;
    int m = idx / N, n = idx % N;
    float s = 0.f;
    for (int k = 0; k < nseg; k++) s += pacc[((size_t)k * 2 + m) * N + n];
    s += bias[n];
    if constexpr (MODE == 4) {
        if (n < 1024) u0[(size_t)m * 1024 + n] = f2bf(s);
        else if (n < 2048) u1[(size_t)(m * T_ + c0) * 1024 + (n - 1024)] = f2bf(s);
        else {
            int id2 = n - 2048, h = id2 >> 6, d = id2 & 63;
            u2[(size_t)((m * 16 + h) * 64 + d) * T_ + c0] = f2bf(s);
        }
    } else {
        u0[(size_t)m * N + n] = f2bf(gelu_tanh(s));
    }
}

// ---------------- V transpose into global vtc[(b*16+h)*64+d][T] (big passes) ----------------
__global__ __launch_bounds__(256) void k_vtrans(const unsigned short* __restrict__ vcbf,
        unsigned short* __restrict__ vtc, int c0, int range) {
    __shared__ unsigned short ts[64][72];
    int pt = blockIdx.x, h = blockIdx.y, b = blockIdx.z;
    int t = threadIdx.x;
#pragma unroll
    for (int i = 0; i < 2; i++) {
        int idx = t + i * 256;
        int p = idx >> 3, c8 = idx & 7;
        int pos = c0 + pt * 64 + p;
        if (pos < c0 + range) {
            short8 v = *(const short8*)&vcbf[(size_t)(b * T_ + pos) * D_ + h * 64 + c8 * 8];
            *(short8*)&ts[p][c8 * 8] = v;
        }
    }
    __syncthreads();
#pragma unroll
    for (int i = 0; i < 2; i++) {
        int idx = t + i * 256;
        int d = idx >> 3, p8 = idx & 7;
        unsigned short tmp[8];
#pragma unroll
        for (int j = 0; j < 8; j++) tmp[j] = ts[p8 * 8 + j][d];
        int pos0 = c0 + pt * 64 + p8 * 8;
        size_t rb = (size_t)((b * 16 + h) * 64 + d) * T_;
        if (pos0 + 7 < c0 + range) {
            *(short8*)&vtc[rb + pos0] = *(short8*)tmp;
        } else {
            for (int j = 0; j < 8; j++)
                if (pos0 + j < c0 + range) vtc[rb + pos0 + j] = tmp[j];
        }
    }
}

// ---------------- barrier-free MFMA flash attention ----------------
__global__ __launch_bounds__(256) void k_fattn(const unsigned short* __restrict__ qbf,
        const unsigned short* __restrict__ kcbf, const unsigned short* __restrict__ vtc,
        unsigned short* __restrict__ ctxbf, int c0, int range) {
    __shared__ unsigned short pw[4][16][72];
    int tid = threadIdx.x;
    int w = tid >> 6, lane = tid & 63, quad = lane >> 4, l15 = lane & 15;
    int qt = blockIdx.x, h = blockIdx.y, b = blockIdx.z;
    int q0 = qt * 64 + w * 16;
    if (q0 >= range) return;                 // no barriers in this kernel -> safe
    int qtop = q0 + 15; if (qtop >= range) qtop = range - 1;
    int nkt = (c0 + qtop) / 64 + 1;

    int qrow = q0 + l15; if (qrow >= range) qrow = range - 1;
    const unsigned short* qp = qbf + (size_t)(b * range + qrow) * D_ + h * 64 + quad * 8;
    short8 aq0 = *(const short8*)qp;
    short8 aq1 = *(const short8*)(qp + 32);

    floatx4 oacc[4];
#pragma unroll
    for (int dg = 0; dg < 4; dg++)
#pragma unroll
        for (int r = 0; r < 4; r++) oacc[dg][r] = 0.f;
    float m_r[4] = {-1e30f, -1e30f, -1e30f, -1e30f};
    float l_r[4] = {0.f, 0.f, 0.f, 0.f};

    const unsigned short* kb_p = kcbf + (size_t)b * T_ * D_ + h * 64 + quad * 8;
    const unsigned short* vb_p = vtc + (size_t)((b * 16 + h) * 64 + l15) * T_ + quad * 8;

    for (int kt = 0; kt < nkt; kt++) {
        int kb = kt * 64;
        floatx4 s[4];
#pragma unroll
        for (int g = 0; g < 4; g++) {
            const unsigned short* kp = kb_p + (size_t)(kb + g * 16 + l15) * D_;
            short8 bk0 = *(const short8*)kp;
            short8 bk1 = *(const short8*)(kp + 32);
            floatx4 z; z[0] = 0.f; z[1] = 0.f; z[2] = 0.f; z[3] = 0.f;
            z = __builtin_amdgcn_mfma_f32_16x16x32_bf16(aq0, bk0, z, 0, 0, 0);
            s[g] = __builtin_amdgcn_mfma_f32_16x16x32_bf16(aq1, bk1, z, 0, 0, 0);
        }
#pragma unroll
        for (int r = 0; r < 4; r++) {
            int qpos = c0 + q0 + quad * 4 + r;
            float mx = -1e30f;
#pragma unroll
            for (int g = 0; g < 4; g++) {
                int kpos = kb + g * 16 + l15;
                float sv = (kpos <= qpos) ? s[g][r] * 0.125f : -1e30f;
                s[g][r] = sv; mx = fmaxf(mx, sv);
            }
            mx = fmaxf(mx, __shfl_xor(mx, 1));
            mx = fmaxf(mx, __shfl_xor(mx, 2));
            mx = fmaxf(mx, __shfl_xor(mx, 4));
            mx = fmaxf(mx, __shfl_xor(mx, 8));
            float mn = fmaxf(m_r[r], mx);
            float alpha = __expf(m_r[r] - mn);
            m_r[r] = mn;
            float ls = 0.f;
#pragma unroll
            for (int g = 0; g < 4; g++) {
                float p = __expf(s[g][r] - mn);
                s[g][r] = p; ls += p;
            }
            ls += __shfl_xor(ls, 1);
            ls += __shfl_xor(ls, 2);
            ls += __shfl_xor(ls, 4);
            ls += __shfl_xor(ls, 8);
            l_r[r] = l_r[r] * alpha + ls;
#pragma unroll
            for (int dg = 0; dg < 4; dg++) oacc[dg][r] *= alpha;
        }
#pragma unroll
        for (int g = 0; g < 4; g++)
#pragma unroll
            for (int r = 0; r < 4; r++)
                pw[w][quad * 4 + r][g * 16 + l15] = f2bf(s[g][r]);
        short8 ap0 = *(const short8*)&pw[w][l15][quad * 8];
        short8 ap1 = *(const short8*)&pw[w][l15][32 + quad * 8];
#pragma unroll
        for (int dg = 0; dg < 4; dg++) {
            const unsigned short* vp = vb_p + (size_t)(dg * 16) * T_ + kb;
            short8 bv0 = *(const short8*)vp;
            short8 bv1 = *(const short8*)(vp + 32);
            oacc[dg] = __builtin_amdgcn_mfma_f32_16x16x32_bf16(ap0, bv0, oacc[dg], 0, 0, 0);
            oacc[dg] = __builtin_amdgcn_mfma_f32_16x16x32_bf16(ap1, bv1, oacc[dg], 0, 0, 0);
        }
    }
#pragma unroll
    for (int dg = 0; dg < 4; dg++)
#pragma unroll
        for (int r = 0; r < 4; r++) {
            int qloc = q0 + quad * 4 + r;
            if (qloc < range)
                ctxbf[(size_t)(b * range + qloc) * D_ + h * 64 + dg * 16 + l15] =
                    f2bf(oacc[dg][r] / l_r[r]);
        }
}

// ---------------- latent vec fills ----------------
__global__ void k_latent0(const float* __restrict__ hid, const float* __restrict__ lw,
                          float* __restrict__ embeds) {
    int idx = blockIdx.x * 256 + threadIdx.x;
    if (idx >= B_ * D_) return;
    int b = idx / D_, d = idx % D_;
    float w0 = lw[0], w1 = lw[1], w2 = lw[2];
    float mx = fmaxf(w0, fmaxf(w1, w2));
    float e0 = __expf(w0 - mx), e1 = __expf(w1 - mx), e2 = __expf(w2 - mx);
    float inv = 1.0f / (e0 + e1 + e2);
    float v = (e0 * hid[(size_t)(b * T_ + 509) * D_ + d] +
               e1 * hid[(size_t)(b * T_ + 510) * D_ + d] +
               e2 * hid[(size_t)(b * T_ + 511) * D_ + d]) * inv;
    embeds[(size_t)(b * T_ + 512) * D_ + d] = v;
}

__global__ void k_latent1(const float* __restrict__ hid, float* __restrict__ embeds, int tok) {
    int idx = blockIdx.x * 256 + threadIdx.x;
    if (idx >= B_ * D_) return;
    int b = idx / D_, d = idx % D_;
    embeds[(size_t)(b * T_ + tok) * D_ + d] = hid[(size_t)(b * T_ + tok - 1) * D_ + d];
}

// ---------------- loss MFMA GEMM: 256x256 tile, counted-vmcnt 2-deep (r8 skeleton scaled) ----------------
// Parameter scale-up of the r8-verified pipeline (catalog: 256²+2ph = 655-666 TF
// at K=1024 vs our 479): 512 thr / 8 waves (2x4 of 128x64), acc[8][4], LDS 64KB
// dbuf, 4 loads/wave/stage -> same vmcnt(4) semantics. Sync structure UNCHANGED.
// XCD swizzle (1000%8==0, bijective): all 8 row-tiles of a chunk share one L2;
// with the pipeline giving loads a full iteration to land, L2-hits now pay.
__global__ __launch_bounds__(512, 2) void k_loss1m(const unsigned short* __restrict__ hidbf,
        const unsigned short* __restrict__ embedbf, const int* __restrict__ labels,
        float* __restrict__ partm, float* __restrict__ parts, float* __restrict__ llogit) {
    __shared__ short8 As0[1024], Bs0[1024];
    __shared__ short8 As1[1024], Bs1[1024];
    __shared__ int lds_lab[256];
    __shared__ float lds_pm[256][4];
    __shared__ float lds_ps[256][4];
    int tid = threadIdx.x;
    int lane = tid & 63, w = tid >> 6;          // w in 0..7
    int quad = lane >> 4, l15 = lane & 15;
    // XCD swizzle: flat dispatch index -> XCD-contiguous work
    int flat = blockIdx.y * 8 + blockIdx.x;     // 0..999
    int swz = (flat & 7) * 125 + (flat >> 3);   // bijective (1000 = 8*125)
    int chunk = swz >> 3;                       // 0..124 (256-col vocab chunk)
    int rtile = swz & 7;                        // 0..7   (256-row tile)
    int row0 = rtile * 256, v0 = chunk * 256;
    int wr = w >> 2, wc = w & 3;                // wave tile: rows wr*128.., cols wc*64..

    if (tid < 256) {
        int tok = row0 + tid;
        lds_lab[tid] = (tok < NTOK) ? labels[tok + 1 + (tok >= 1023)] : -1;
    }

    // staging: per wave 2 A-slots + 2 B-slots of 64 lanes x 16B.
    // slot c in 0..1023: row = c & 255, kg = c >> 8 (LDS index == c, linear).
    const unsigned short* ga[2];
    const unsigned short* gb[2];
#pragma unroll
    for (int j = 0; j < 2; j++) {
        int c = (w * 2 + j) * 64 + lane;
        int rowi = c & 255, kg = c >> 8;
        int tokA = row0 + rowi; if (tokA >= NTOK) tokA = NTOK - 1;
        ga[j] = hidbf + (size_t)(tokA + (tokA >= 1023)) * D_ + kg * 8;
        gb[j] = embedbf + (size_t)(v0 + rowi) * D_ + kg * 8;
    }

    floatx4 acc[8][4];
#pragma unroll
    for (int i = 0; i < 8; i++)
#pragma unroll
        for (int j = 0; j < 4; j++)
#pragma unroll
            for (int k = 0; k < 4; k++) acc[i][j][k] = 0.f;

#define LSTAGE(AS, BS) \
    gld_lds16(&AS[(w * 2 + 0) * 64], ga[0]); \
    gld_lds16(&AS[(w * 2 + 1) * 64], ga[1]); \
    gld_lds16(&BS[(w * 2 + 0) * 64], gb[0]); \
    gld_lds16(&BS[(w * 2 + 1) * 64], gb[1]); \
    ga[0] += 32; ga[1] += 32; gb[0] += 32; gb[1] += 32;

#define LCOMP(AS, BS) { \
    short8 af[8], bfv[4]; \
    _Pragma("unroll") \
    for (int mi = 0; mi < 8; mi++) af[mi] = AS[quad * 256 + wr * 128 + mi * 16 + l15]; \
    _Pragma("unroll") \
    for (int nj = 0; nj < 4; nj++) bfv[nj] = BS[quad * 256 + wc * 64 + nj * 16 + l15]; \
    _Pragma("unroll") \
    for (int mi = 0; mi < 8; mi++) \
        _Pragma("unroll") \
        for (int nj = 0; nj < 4; nj++) \
            acc[mi][nj] = __builtin_amdgcn_mfma_f32_16x16x32_bf16(af[mi], bfv[nj], acc[mi][nj], 0, 0, 0); }

#define WAIT_VM4_BAR \
    asm volatile("s_waitcnt vmcnt(4)" ::: "memory"); \
    __builtin_amdgcn_s_barrier(); \
    __builtin_amdgcn_sched_barrier(0);

#define WAIT_LGKM_BAR \
    asm volatile("s_waitcnt lgkmcnt(0)" ::: "memory"); \
    __builtin_amdgcn_s_barrier(); \
    __builtin_amdgcn_sched_barrier(0);

    // prologue: tile0 -> buf0 (4 loads in flight)
    LSTAGE(As0, Bs0)
    // main: 15 pairs = tiles 0..29 computed, tiles 1..30 staged
    for (int itp = 0; itp < 15; ++itp) {
        LSTAGE(As1, Bs1)
        WAIT_VM4_BAR
        LCOMP(As0, Bs0)
        WAIT_LGKM_BAR
        LSTAGE(As0, Bs0)
        WAIT_VM4_BAR
        LCOMP(As1, Bs1)
        WAIT_LGKM_BAR
    }
    LSTAGE(As1, Bs1)
    WAIT_VM4_BAR
    LCOMP(As0, Bs0)
    WAIT_LGKM_BAR
    asm volatile("s_waitcnt vmcnt(0)" ::: "memory");
    __builtin_amdgcn_s_barrier();
    __builtin_amdgcn_sched_barrier(0);
    LCOMP(As1, Bs1)

#undef LSTAGE
#undef LCOMP
#undef WAIT_VM4_BAR
#undef WAIT_LGKM_BAR

    // per-row softmax partials over this wave's 64-col slice; 4 waves (wc=0..3)
    // cover the chunk's 256 cols for each 128-row band -> lds_pm[rloc][wc].
#pragma unroll
    for (int mi = 0; mi < 8; mi++)
#pragma unroll
        for (int reg = 0; reg < 4; reg++) {
            int rloc = wr * 128 + mi * 16 + quad * 4 + reg;
            int lab = lds_lab[rloc];
            float vm = -1e30f;
#pragma unroll
            for (int nj = 0; nj < 4; nj++) {
                float v = acc[mi][nj][reg];
                int vcol = v0 + wc * 64 + nj * 16 + l15;
                if (vcol == lab) llogit[row0 + rloc] = v;
                vm = fmaxf(vm, v);
            }
            for (int off = 1; off < 16; off <<= 1) vm = fmaxf(vm, __shfl_xor(vm, off));
            float ss = 0.f;
#pragma unroll
            for (int nj = 0; nj < 4; nj++) ss += __expf(acc[mi][nj][reg] - vm);
            for (int off = 1; off < 16; off <<= 1) ss += __shfl_xor(ss, off);
            if (l15 == 0) { lds_pm[rloc][wc] = vm; lds_ps[rloc][wc] = ss; }
        }
    __syncthreads();
    if (tid < 256) {
        int tok = row0 + tid;
        if (tok < NTOK) {
            float m0 = fmaxf(lds_pm[tid][0], lds_pm[tid][1]);
            float m1 = fmaxf(lds_pm[tid][2], lds_pm[tid][3]);
            float M = fmaxf(m0, m1);
            float S = lds_ps[tid][0] * __expf(lds_pm[tid][0] - M)
                    + lds_ps[tid][1] * __expf(lds_pm[tid][1] - M)
                    + lds_ps[tid][2] * __expf(lds_pm[tid][2] - M)
                    + lds_ps[tid][3] * __expf(lds_pm[tid][3] - M);
            partm[(size_t)chunk * NTOK + tok] = M;
            parts[(size_t)chunk * NTOK + tok] = S;
        }
    }
}

// ---------------- loss combine ----------------
__global__ void k_loss2a(const float* __restrict__ partm, const float* __restrict__ parts,
                         const float* __restrict__ ll, float* __restrict__ nll) {
    int tok = blockIdx.x * 256 + threadIdx.x;
    if (tok >= NTOK) return;
    float M = -1e30f;
    for (int c = 0; c < NCH; c++) M = fmaxf(M, partm[(size_t)c * NTOK + tok]);
    float S = 0.f;
    for (int c = 0; c < NCH; c++)
        S += parts[(size_t)c * NTOK + tok] * __expf(partm[(size_t)c * NTOK + tok] - M);
    nll[tok] = logf(S) + M - ll[tok];
}

__global__ __launch_bounds__(256) void k_loss2b(const float* __restrict__ nll, float* __restrict__ out) {
    __shared__ float red[256];
    int tid = threadIdx.x;
    float s = 0.f;
    for (int i = tid; i < NTOK; i += 256) s += nll[i];
    red[tid] = s; __syncthreads();
    for (int o = 128; o > 0; o >>= 1) {
        if (tid < o) red[tid] += red[tid + o];
        __syncthreads();
    }
    if (tid == 0) out[0] = red[0] / (float)NTOK;
}

// ---------------- host ----------------
extern "C" void kernel_launch(void* const* d_in, const int* in_sizes, int n_in,
                              void* d_out, int out_size, void* d_ws, size_t ws_size,
                              hipStream_t stream) {
    const int*   input_ids = (const int*)d_in[0];
    const int*   labels    = (const int*)d_in[2];
    const float* embed     = (const float*)d_in[4];
    const float* Wpos      = (const float*)d_in[5];
    const float* Wqkv      = (const float*)d_in[6];
    const float* bqkv      = (const float*)d_in[7];
    const float* Aq        = (const float*)d_in[8];
    const float* Bq        = (const float*)d_in[9];
    const float* Wo        = (const float*)d_in[10];
    const float* bo        = (const float*)d_in[11];
    const float* Ao        = (const float*)d_in[12];
    const float* Bo        = (const float*)d_in[13];
    const float* W1        = (const float*)d_in[14];
    const float* b1        = (const float*)d_in[15];
    const float* W2        = (const float*)d_in[16];
    const float* b2        = (const float*)d_in[17];
    const float* ln1_s     = (const float*)d_in[18];
    const float* ln1_b     = (const float*)d_in[19];
    const float* ln2_s     = (const float*)d_in[20];
    const float* ln2_b     = (const float*)d_in[21];
    const float* lnf_s     = (const float*)d_in[22];
    const float* lnf_b     = (const float*)d_in[23];
    const float* latent_w  = (const float*)d_in[24];

    char* base = (char*)d_ws;
    size_t off = 0;
    auto alloc = [&](size_t bytes) { void* p = base + off; off += (bytes + 255) & ~255ULL; return p; };

    float* embeds  = (float*)alloc((size_t)B_ * T_ * D_ * 4);
    float* hbuf    = (float*)alloc((size_t)B_ * T_ * D_ * 4);
    float* hidbuf  = (float*)alloc((size_t)B_ * T_ * D_ * 4);
    float* partm   = (float*)alloc((size_t)NCH * NTOK * 4);
    float* parts_  = (float*)alloc((size_t)NCH * NTOK * 4);
    float* llogit  = (float*)alloc((size_t)NTOK * 4);
    float* nllbuf  = (float*)alloc((size_t)NTOK * 4);
    float* pacc    = (float*)alloc((size_t)16 * 2 * 4096 * 4);   // tiny-pass partials
    unsigned short* wqkvT  = (unsigned short*)alloc((size_t)3072 * 1024 * 2);
    unsigned short* woT    = (unsigned short*)alloc((size_t)1024 * 1024 * 2);
    unsigned short* W1T    = (unsigned short*)alloc((size_t)4096 * 1024 * 2);
    unsigned short* W2T    = (unsigned short*)alloc((size_t)1024 * 4096 * 2);
    unsigned short* embedbf = (unsigned short*)alloc((size_t)V_ * D_ * 2);
    unsigned short* hidbf  = (unsigned short*)alloc((size_t)B_ * T_ * D_ * 2);
    unsigned short* abf    = (unsigned short*)alloc((size_t)1024 * D_ * 2);
    unsigned short* ctxbf  = (unsigned short*)alloc((size_t)1024 * D_ * 2);
    unsigned short* ffbw   = (unsigned short*)alloc((size_t)1024 * DFF_ * 2);
    unsigned short* qbf    = (unsigned short*)alloc((size_t)1024 * D_ * 2);
    unsigned short* kcbf   = (unsigned short*)alloc((size_t)B_ * T_ * D_ * 2);
    unsigned short* vcbf   = (unsigned short*)alloc((size_t)B_ * T_ * D_ * 2);
    unsigned short* vtc    = (unsigned short*)alloc((size_t)B_ * H_ * DH_ * T_ * 2);

    // weight prep (transpose + LoRA merge + bf16)
    k_prep_w<<<dim3(3072 / 64, 1024 / 64), 256, 0, stream>>>(Wqkv, Aq, Bq, wqkvT, 1024, 3072, 1);
    k_prep_w<<<dim3(1024 / 64, 1024 / 64), 256, 0, stream>>>(Wo, Ao, Bo, woT, 1024, 1024, 1);
    k_prep_w<<<dim3(4096 / 64, 1024 / 64), 256, 0, stream>>>(W1, nullptr, nullptr, W1T, 1024, 4096, 0);
    k_prep_w<<<dim3(1024 / 64, 4096 / 64), 256, 0, stream>>>(W2, nullptr, nullptr, W2T, 4096, 1024, 0);
    k_f2bf<<<(V_ * D_ / 4 + 255) / 256, 256, 0, stream>>>(embed, embedbf, V_ * D_ / 4);
    k_embed_gather<<<B_ * T_, 256, 0, stream>>>(input_ids, embed, embeds);

    auto run_pass = [&](int c0, int c1) {
        int range = c1 - c0;
        int Mr = B_ * range;
        int gy = (Mr + 63) / 64;
        int qt = (range + 63) / 64;
        // ln1 (fused h = embeds + Wpos -> hbuf)
        k_ln<<<Mr, 256, 0, stream>>>(nullptr, embeds, Wpos, ln1_s, ln1_b, hbuf, nullptr, abf, c0, range, 0);
        if (range == 1) {
            // tiny pass: chip-wide K-split GEMVs (grid = cols/64 x K/256)
            k_sp_part<<<dim3(48, 4), 256, 0, stream>>>(abf, wqkvT, pacc, 3072, 1024);
            k_sp_fin<4><<<24, 256, 0, stream>>>(pacc, bqkv, qbf, kcbf, vtc, 3072, 4, c0);
            k_fattn<<<dim3(1, H_, B_), 256, 0, stream>>>(qbf, kcbf, vtc, ctxbf, c0, 1);
            k_sp_add<<<dim3(16, 4), 256, 0, stream>>>(ctxbf, woT, bo, hbuf, 1024, 1024, c0);
            k_ln<<<Mr, 256, 0, stream>>>(hbuf, nullptr, nullptr, ln2_s, ln2_b, nullptr, nullptr, abf, c0, range, 0);
            k_sp_part<<<dim3(64, 4), 256, 0, stream>>>(abf, W1T, pacc, 4096, 1024);
            k_sp_fin<3><<<32, 256, 0, stream>>>(pacc, b1, ffbw, nullptr, nullptr, 4096, 4, c0);
            k_sp_add<<<dim3(16, 16), 256, 0, stream>>>(ffbw, W2T, b2, hbuf, 1024, 4096, c0);
        } else {
            k_mgemm<1><<<dim3(3072 / 128, gy), 256, 0, stream>>>(abf, wqkvT, bqkv, nullptr, qbf, kcbf, vcbf,
                                                                 Mr, 3072, 1024, c0, range, 1);
            k_vtrans<<<dim3(qt, H_, B_), 256, 0, stream>>>(vcbf, vtc, c0, range);
            k_fattn<<<dim3(qt, H_, B_), 256, 0, stream>>>(qbf, kcbf, vtc, ctxbf, c0, range);
            k_mgemm<2><<<dim3(1024 / 128, gy, 4), 256, 0, stream>>>(ctxbf, woT, bo, hbuf, nullptr, nullptr, nullptr,
                                                                    Mr, 1024, 1024, c0, range, 4);
            k_ln<<<Mr, 256, 0, stream>>>(hbuf, nullptr, nullptr, ln2_s, ln2_b, nullptr, nullptr, abf, c0, range, 0);
            k_mgemm<3><<<dim3(4096 / 128, gy), 256, 0, stream>>>(abf, W1T, b1, nullptr, ffbw, nullptr, nullptr,
                                                                 Mr, 4096, 1024, c0, range, 1);
            k_mgemm<2><<<dim3(1024 / 128, gy, 4), 256, 0, stream>>>(ffbw, W2T, b2, hbuf, nullptr, nullptr, nullptr,
                                                                    Mr, 1024, 4096, c0, range, 4);
        }
        k_ln<<<Mr, 256, 0, stream>>>(hbuf, nullptr, nullptr, lnf_s, lnf_b, nullptr, hidbuf, hidbf, c0, range, 1);
    };

    run_pass(0, 512);
    k_latent0<<<(B_ * D_ + 255) / 256, 256, 0, stream>>>(hidbuf, latent_w, embeds);
    run_pass(512, 513);
    k_latent1<<<(B_ * D_ + 255) / 256, 256, 0, stream>>>(hidbuf, embeds, 513);
    run_pass(513, 514);
    k_latent1<<<(B_ * D_ + 255) / 256, 256, 0, stream>>>(hidbuf, embeds, 514);
    run_pass(514, 515);
    k_latent1<<<(B_ * D_ + 255) / 256, 256, 0, stream>>>(hidbuf, embeds, 515);
    run_pass(515, 1024);

    // loss: grid x = row tiles (8 x 256 rows), y = vocab chunks (125 x 256 cols)
    k_loss1m<<<dim3(8, NCH), 512, 0, stream>>>(hidbf, embedbf, labels, partm, parts_, llogit);
    k_loss2a<<<(NTOK + 255) / 256, 256, 0, stream>>>(partm, parts_, llogit, nllbuf);
    k_loss2b<<<1, 256, 0, stream>>>(nllbuf, (float*)d_out);
}